// Round 3
// baseline (7575.858 us; speedup 1.0000x reference)
//
#include <hip/hip_runtime.h>

// GIN: 5 layers, DIM=10. Identity: (x+agg)@W1 = x@W1 + segsum((x@W1)[src]).
// R3: two-level bucketed CSR build (L2-mergeable writes) + 4-way unrolled
// gather in the fused layer kernel. y rows padded to 16 floats (64B lines).

// ---------------- Layer-1: y = h @ W1_1   (h:[N,64], W1:[64,10]) ----------------
template<int PAD>
__global__ void k1_hw1(const float* __restrict__ h, const float* __restrict__ W1,
                       float* __restrict__ y, int N) {
    __shared__ float sW[640];
    for (int i = threadIdx.x; i < 640; i += blockDim.x) sW[i] = W1[i];
    __syncthreads();
    int n = blockIdx.x * blockDim.x + threadIdx.x;
    if (n >= N) return;
    const float* hr = h + (size_t)n * 64;
    float acc[10];
#pragma unroll
    for (int j = 0; j < 10; j++) acc[j] = 0.f;
#pragma unroll 4
    for (int k = 0; k < 64; k += 4) {
        float4 hv = *(const float4*)(hr + k);
#pragma unroll
        for (int j = 0; j < 10; j++) {
            acc[j] += hv.x * sW[(k + 0) * 10 + j];
            acc[j] += hv.y * sW[(k + 1) * 10 + j];
            acc[j] += hv.z * sW[(k + 2) * 10 + j];
            acc[j] += hv.w * sW[(k + 3) * 10 + j];
        }
    }
    float* yr = y + (size_t)n * PAD;
#pragma unroll
    for (int j = 0; j < 10; j++) yr[j] = acc[j];
}

// =================== R3 CSR build: two-level bucket split ===================
// bucket b = dst >> 10 (1024 nodes per bucket). B = ceil(N/1024) buckets.

__global__ void k_bhist(const int* __restrict__ dst, unsigned* __restrict__ bucket_cnt,
                        int E) {
    __shared__ unsigned h[512];
    int t = threadIdx.x;
    h[t] = 0; h[t + 256] = 0;
    __syncthreads();
    int stride = gridDim.x * blockDim.x;
    for (int e = blockIdx.x * blockDim.x + t; e < E; e += stride)
        atomicAdd(&h[(unsigned)dst[e] >> 10], 1u);
    __syncthreads();
    if (h[t]) atomicAdd(&bucket_cnt[t], h[t]);
    if (h[t + 256]) atomicAdd(&bucket_cnt[t + 256], h[t + 256]);
}

// exclusive scan of bucket_cnt (B <= 512) -> bbase[0..B], copy into bcur
__global__ void k_bscan(const unsigned* __restrict__ bucket_cnt,
                        unsigned* __restrict__ bbase, unsigned* __restrict__ bcur, int B) {
    __shared__ unsigned s[512];
    int t = threadIdx.x;
    unsigned v = (t < B) ? bucket_cnt[t] : 0u;
    s[t] = v;
    __syncthreads();
    for (int off = 1; off < 512; off <<= 1) {
        unsigned u = (t >= off) ? s[t - off] : 0u;
        __syncthreads();
        s[t] += u;
        __syncthreads();
    }
    unsigned excl = s[t] - v;
    if (t < B) { bbase[t] = excl; bcur[t] = excl; }
    if (t == B - 1) bbase[B] = s[t];
}

// coarse scatter: pairs[pos] = (src << 10) | (dst & 1023), bucket-ordered.
// Only ~489 active write streams -> frontier lines stay in L2 and merge.
__global__ void k_bscatter(const int* __restrict__ src, const int* __restrict__ dst,
                           unsigned* __restrict__ bcur, unsigned* __restrict__ pairs, int E) {
    int stride = gridDim.x * blockDim.x;
    for (int e = blockIdx.x * blockDim.x + threadIdx.x; e < E; e += stride) {
        unsigned d = (unsigned)dst[e];
        unsigned pos = atomicAdd(&bcur[d >> 10], 1u);
        pairs[pos] = ((unsigned)src[e] << 10) | (d & 1023u);
    }
}

// fine pass: one block per bucket. LDS hist + scan -> row_start; scatter src
// into edges[] within the bucket's contiguous window (single-CU writes merge).
__global__ __launch_bounds__(1024) void k_p2(
        const unsigned* __restrict__ pairs, const unsigned* __restrict__ bbase,
        unsigned* __restrict__ edges, unsigned* __restrict__ row_start,
        int N, int B, int E) {
    __shared__ unsigned cnt[1024], scn[1024], cur[1024];
    int t = threadIdx.x, b = blockIdx.x;
    unsigned beg = bbase[b], end = bbase[b + 1];
    cnt[t] = 0;
    __syncthreads();
    for (unsigned e = beg + t; e < end; e += 1024)
        atomicAdd(&cnt[pairs[e] & 1023u], 1u);
    __syncthreads();
    unsigned v = cnt[t];
    scn[t] = v;
    __syncthreads();
    for (int off = 1; off < 1024; off <<= 1) {
        unsigned u = (t >= off) ? scn[t - off] : 0u;
        __syncthreads();
        scn[t] += u;
        __syncthreads();
    }
    unsigned excl = scn[t] - v;
    int node = (b << 10) + t;
    if (node < N) row_start[node] = beg + excl;
    if (b == B - 1 && t == 0) row_start[N] = (unsigned)E;
    cur[t] = beg + excl;
    __syncthreads();
    for (unsigned e = beg + t; e < end; e += 1024) {
        unsigned pv = pairs[e];
        unsigned pos = atomicAdd(&cur[pv & 1023u], 1u);
        edges[pos] = pv >> 10;
    }
}

// ------- Fused layer: acc = y[n] + sum_{in-edges} y[src]; z=relu(acc+b1);
//         x=relu(z@W2+b2); p=x.l -> gacc; yout = x@W1_next -------
// row_start has N+1 entries (row_start[N] == E).
__global__ __launch_bounds__(256) void k_layer(
        const float* __restrict__ yin, float* __restrict__ yout,
        const unsigned* __restrict__ row_start, const unsigned* __restrict__ edges,
        const float* __restrict__ b1, const float* __restrict__ W2,
        const float* __restrict__ b2, const float* __restrict__ l,
        const float* __restrict__ W1n,
        const int* __restrict__ node_graph, float* __restrict__ gacc,
        int N, int last) {
    __shared__ float sW2[100], sW1[100], sb1[10], sb2[10], sl[10];
    int t = threadIdx.x;
    if (t < 100) sW2[t] = W2[t];
    if (!last && t >= 128 && t < 228) sW1[t - 128] = W1n[t - 128];
    if (t < 10) { sb1[t] = b1[t]; sb2[t] = b2[t]; sl[t] = l[t]; }
    __syncthreads();
    int n = blockIdx.x * 256 + t;
    bool valid = n < N;
    int nc = valid ? n : (N - 1);

    const float* yr = yin + (size_t)nc * 16;
    float4 a = *(const float4*)yr;
    float4 b = *(const float4*)(yr + 4);
    float2 c = *(const float2*)(yr + 8);
    float acc[10] = {a.x, a.y, a.z, a.w, b.x, b.y, b.z, b.w, c.x, c.y};

    unsigned beg = 0, end = 0;
    if (valid) { beg = row_start[n]; end = row_start[n + 1]; }

    unsigned e = beg;
    // 4-edge batches: 4 id loads then 12 independent row loads in flight
    for (; e + 4 <= end; e += 4) {
        unsigned s0 = edges[e + 0], s1 = edges[e + 1];
        unsigned s2 = edges[e + 2], s3 = edges[e + 3];
        const float* p0 = yin + (size_t)s0 * 16;
        const float* p1 = yin + (size_t)s1 * 16;
        const float* p2 = yin + (size_t)s2 * 16;
        const float* p3 = yin + (size_t)s3 * 16;
        float4 a0 = *(const float4*)p0, b0 = *(const float4*)(p0 + 4);
        float4 a1 = *(const float4*)p1, b1v = *(const float4*)(p1 + 4);
        float4 a2 = *(const float4*)p2, b2v = *(const float4*)(p2 + 4);
        float4 a3 = *(const float4*)p3, b3 = *(const float4*)(p3 + 4);
        float2 c0 = *(const float2*)(p0 + 8), c1 = *(const float2*)(p1 + 8);
        float2 c2 = *(const float2*)(p2 + 8), c3 = *(const float2*)(p3 + 8);
        acc[0] += (a0.x + a1.x) + (a2.x + a3.x);
        acc[1] += (a0.y + a1.y) + (a2.y + a3.y);
        acc[2] += (a0.z + a1.z) + (a2.z + a3.z);
        acc[3] += (a0.w + a1.w) + (a2.w + a3.w);
        acc[4] += (b0.x + b1v.x) + (b2v.x + b3.x);
        acc[5] += (b0.y + b1v.y) + (b2v.y + b3.y);
        acc[6] += (b0.z + b1v.z) + (b2v.z + b3.z);
        acc[7] += (b0.w + b1v.w) + (b2v.w + b3.w);
        acc[8] += (c0.x + c1.x) + (c2.x + c3.x);
        acc[9] += (c0.y + c1.y) + (c2.y + c3.y);
    }
    for (; e < end; ++e) {
        unsigned s = edges[e];
        const float* pr = yin + (size_t)s * 16;
        float4 pa = *(const float4*)pr;
        float4 pb = *(const float4*)(pr + 4);
        float2 pc = *(const float2*)(pr + 8);
        acc[0] += pa.x; acc[1] += pa.y; acc[2] += pa.z; acc[3] += pa.w;
        acc[4] += pb.x; acc[5] += pb.y; acc[6] += pb.z; acc[7] += pb.w;
        acc[8] += pc.x; acc[9] += pc.y;
    }

    float z[10], x[10];
#pragma unroll
    for (int j = 0; j < 10; j++) {
        float v = acc[j] + sb1[j];
        z[j] = v > 0.f ? v : 0.f;
    }
#pragma unroll
    for (int j = 0; j < 10; j++) {
        float v = sb2[j];
#pragma unroll
        for (int k = 0; k < 10; k++) v += z[k] * sW2[k * 10 + j];
        x[j] = v > 0.f ? v : 0.f;
    }
    float p = 0.f;
#pragma unroll
    for (int j = 0; j < 10; j++) p += x[j] * sl[j];
    if (!valid) p = 0.f;
    int g = node_graph[nc];

    int g0 = __shfl(g, 0);
    if (__all(g == g0)) {
#pragma unroll
        for (int off = 32; off > 0; off >>= 1) p += __shfl_down(p, off);
        if ((t & 63) == 0) unsafeAtomicAdd(&gacc[g0], p);
    } else {
        if (valid) unsafeAtomicAdd(&gacc[g], p);
    }

    if (!last && valid) {
        float yn[10];
#pragma unroll
        for (int j = 0; j < 10; j++) {
            float v = 0.f;
#pragma unroll
            for (int k = 0; k < 10; k++) v += x[k] * sW1[k * 10 + j];
            yn[j] = v;
        }
        float* yo = yout + (size_t)n * 16;
#pragma unroll
        for (int j = 0; j < 10; j++) yo[j] = yn[j];
    }
}

// ---------------- Final: out[g] = sigmoid(gacc[g] / max(count,1)) ----------------
__global__ void k4_final(const float* __restrict__ gacc, const int* __restrict__ node_graph,
                         float* __restrict__ out, int N, int G) {
    int g = blockIdx.x * blockDim.x + threadIdx.x;
    if (g >= G) return;
    int lo = 0, hi = N;
    while (lo < hi) { int m = (lo + hi) >> 1; if (node_graph[m] < g) lo = m + 1; else hi = m; }
    int lo2 = lo, hi2 = N;
    while (lo2 < hi2) { int m = (lo2 + hi2) >> 1; if (node_graph[m] <= g) lo2 = m + 1; else hi2 = m; }
    float c = (float)(hi2 - lo);
    if (c < 1.f) c = 1.f;
    float s = gacc[g] / c;
    out[g] = 1.f / (1.f + __expf(-s));
}

// =================== R2 fallback CSR build (per-node atomics) ===================
__global__ void k_hist(const int* __restrict__ dst, unsigned* __restrict__ cnt, int E) {
    int stride = gridDim.x * blockDim.x;
    for (int e = blockIdx.x * blockDim.x + threadIdx.x; e < E; e += stride)
        atomicAdd(&cnt[dst[e]], 1u);
}

__global__ void k_scan1(unsigned* __restrict__ data, unsigned* __restrict__ bsums, int N) {
    __shared__ unsigned tmp[1024];
    int t = threadIdx.x;
    int idx = blockIdx.x * 1024 + t;
    unsigned v = (idx < N) ? data[idx] : 0u;
    tmp[t] = v;
    __syncthreads();
    for (int off = 1; off < 1024; off <<= 1) {
        unsigned u = (t >= off) ? tmp[t - off] : 0u;
        __syncthreads();
        tmp[t] += u;
        __syncthreads();
    }
    if (idx < N) data[idx] = tmp[t] - v;
    if (t == 1023) bsums[blockIdx.x] = tmp[1023];
}

__global__ void k_scan2(unsigned* __restrict__ bsums, int nb) {
    __shared__ unsigned tmp[1024];
    int t = threadIdx.x;
    unsigned v = (t < nb) ? bsums[t] : 0u;
    tmp[t] = v;
    __syncthreads();
    for (int off = 1; off < 1024; off <<= 1) {
        unsigned u = (t >= off) ? tmp[t - off] : 0u;
        __syncthreads();
        tmp[t] += u;
        __syncthreads();
    }
    if (t < nb) bsums[t] = tmp[t] - v;
}

__global__ void k_scan3(unsigned* __restrict__ data, const unsigned* __restrict__ bsums,
                        unsigned* __restrict__ cursor, int N, int E) {
    int n = blockIdx.x * blockDim.x + threadIdx.x;
    if (n > N) return;
    if (n == N) { data[N] = (unsigned)E; return; }
    unsigned v = data[n] + bsums[n >> 10];
    data[n] = v;
    cursor[n] = v;
}

__global__ void k_scatter(const int* __restrict__ src, const int* __restrict__ dst,
                          unsigned* __restrict__ cursor, unsigned* __restrict__ edges, int E) {
    int stride = gridDim.x * blockDim.x;
    for (int e = blockIdx.x * blockDim.x + threadIdx.x; e < E; e += stride) {
        unsigned pos = atomicAdd(&cursor[dst[e]], 1u);
        edges[pos] = (unsigned)src[e];
    }
}

extern "C" void kernel_launch(void* const* d_in, const int* in_sizes, int n_in,
                              void* d_out, int out_size, void* d_ws, size_t ws_size,
                              hipStream_t stream) {
    const float* h  = (const float*)d_in[0];
    const int* src  = (const int*)d_in[1];
    const int* dst  = (const int*)d_in[2];
    const int* ng   = (const int*)d_in[3];
    int N = in_sizes[3];
    int E = in_sizes[1];
    int G = out_size;

    const float* W1[5]; const float* b1[5]; const float* W2[5]; const float* b2[5]; const float* l[5];
    for (int i = 0; i < 5; i++) {
        W1[i] = (const float*)d_in[4 + i * 5 + 0];
        b1[i] = (const float*)d_in[4 + i * 5 + 1];
        W2[i] = (const float*)d_in[4 + i * 5 + 2];
        b2[i] = (const float*)d_in[4 + i * 5 + 3];
        l[i]  = (const float*)d_in[4 + i * 5 + 4];
    }
    float* out = (float*)d_out;

    int B = (N + 1023) >> 10;  // buckets of 1024 nodes

    // R3 layout (4B units):
    //   y0[N*16] | region2 = max(pairs[E], y1[N*16]) | edges[E] | row_start[N+1]
    //   | bucket_cnt[512] | bbase[513] | bcur[512] | gacc[G]
    size_t regAB = (size_t)N * 16;
    size_t reg2 = ((size_t)E > (size_t)N * 16) ? (size_t)E : (size_t)N * 16;
    size_t need_r3 = (regAB + reg2 + (size_t)E + (size_t)(N + 1) + 1537 + (size_t)G) * 4;

    if (ws_size >= need_r3 && B <= 512) {
        float* y0 = (float*)d_ws;
        unsigned* pairs = (unsigned*)(y0 + regAB);
        float* y1 = (float*)pairs;  // pairs dead after k_p2
        unsigned* edges = pairs + reg2;
        unsigned* row_start = edges + E;
        unsigned* bucket_cnt = row_start + (N + 1);
        unsigned* bbase = bucket_cnt + 512;
        unsigned* bcur = bbase + 513;
        float* gacc = (float*)(bcur + 512);

        hipMemsetAsync(bucket_cnt, 0, 512 * 4, stream);
        hipMemsetAsync(gacc, 0, (size_t)G * 4, stream);

        k1_hw1<16><<<(N + 255) / 256, 256, 0, stream>>>(h, W1[0], y0, N);

        k_bhist<<<2048, 256, 0, stream>>>(dst, bucket_cnt, E);
        k_bscan<<<1, 512, 0, stream>>>(bucket_cnt, bbase, bcur, B);
        k_bscatter<<<2048, 256, 0, stream>>>(src, dst, bcur, pairs, E);
        k_p2<<<B, 1024, 0, stream>>>(pairs, bbase, edges, row_start, N, B, E);

        float* ybuf[2] = {y0, y1};
        for (int i = 0; i < 5; i++) {
            k_layer<<<(N + 255) / 256, 256, 0, stream>>>(
                ybuf[i & 1], ybuf[(i + 1) & 1], row_start, edges,
                b1[i], W2[i], b2[i], l[i], i < 4 ? W1[i + 1] : nullptr,
                ng, gacc, N, i == 4 ? 1 : 0);
        }
        k4_final<<<(G + 255) / 256, 256, 0, stream>>>(gacc, ng, out, N, G);
        return;
    }

    // R2 fallback: per-node atomic CSR build
    //   y0[N*16] | y1[N*16] | row_start[N+1] | cursor[N] | bsums[1024] | edges[E] | gacc[G]
    float* y0 = (float*)d_ws;
    float* y1 = y0 + (size_t)N * 16;
    unsigned* row_start = (unsigned*)(y1 + (size_t)N * 16);
    unsigned* cursor = row_start + (N + 1);
    unsigned* bsums = cursor + N;
    unsigned* edges = bsums + 1024;
    float* gacc = (float*)(edges + E);

    hipMemsetAsync(row_start, 0, (size_t)N * 4, stream);
    hipMemsetAsync(gacc, 0, (size_t)G * 4, stream);

    k1_hw1<16><<<(N + 255) / 256, 256, 0, stream>>>(h, W1[0], y0, N);

    k_hist<<<2048, 256, 0, stream>>>(dst, row_start, E);
    int nb = (N + 1023) / 1024;
    k_scan1<<<nb, 1024, 0, stream>>>(row_start, bsums, N);
    k_scan2<<<1, 1024, 0, stream>>>(bsums, nb);
    k_scan3<<<(N + 256) / 256, 256, 0, stream>>>(row_start, bsums, cursor, N, E);
    k_scatter<<<2048, 256, 0, stream>>>(src, dst, cursor, edges, E);

    float* ybuf[2] = {y0, y1};
    for (int i = 0; i < 5; i++) {
        k_layer<<<(N + 255) / 256, 256, 0, stream>>>(
            ybuf[i & 1], ybuf[(i + 1) & 1], row_start, edges,
            b1[i], W2[i], b2[i], l[i], i < 4 ? W1[i + 1] : nullptr,
            ng, gacc, N, i == 4 ? 1 : 0);
    }
    k4_final<<<(G + 255) / 256, 256, 0, stream>>>(gacc, ng, out, N, G);
}

// Round 4
// 3102.443 us; speedup vs baseline: 2.4419x; 2.4419x over previous
//
#include <hip/hip_runtime.h>

// GIN: 5 layers, DIM=10. Identity: (x+agg)@W1 = x@W1 + segsum((x@W1)[src]).
// R4: bucketed CSR build with BLOCK-AGGREGATED cursor reservation (fixes R3's
// 489-address atomic contention while keeping L2-mergeable bucket-ordered
// writes) + vectorized yout store in the fused layer kernel.

// ---------------- Layer-1: y = h @ W1_1   (h:[N,64], W1:[64,10]) ----------------
template<int PAD>
__global__ void k1_hw1(const float* __restrict__ h, const float* __restrict__ W1,
                       float* __restrict__ y, int N) {
    __shared__ float sW[640];
    for (int i = threadIdx.x; i < 640; i += blockDim.x) sW[i] = W1[i];
    __syncthreads();
    int n = blockIdx.x * blockDim.x + threadIdx.x;
    if (n >= N) return;
    const float* hr = h + (size_t)n * 64;
    float acc[10];
#pragma unroll
    for (int j = 0; j < 10; j++) acc[j] = 0.f;
#pragma unroll 4
    for (int k = 0; k < 64; k += 4) {
        float4 hv = *(const float4*)(hr + k);
#pragma unroll
        for (int j = 0; j < 10; j++) {
            acc[j] += hv.x * sW[(k + 0) * 10 + j];
            acc[j] += hv.y * sW[(k + 1) * 10 + j];
            acc[j] += hv.z * sW[(k + 2) * 10 + j];
            acc[j] += hv.w * sW[(k + 3) * 10 + j];
        }
    }
    float* yr = y + (size_t)n * PAD;
#pragma unroll
    for (int j = 0; j < 10; j++) yr[j] = acc[j];
}

// =================== CSR build: two-level bucket split ===================
// bucket b = dst >> 10 (1024 nodes per bucket). B = ceil(N/1024) <= 512.

__global__ void k_bhist(const int* __restrict__ dst, unsigned* __restrict__ bucket_cnt,
                        int E) {
    __shared__ unsigned h[512];
    int t = threadIdx.x;
    h[t] = 0; h[t + 256] = 0;
    __syncthreads();
    int stride = gridDim.x * blockDim.x;
    for (int e = blockIdx.x * blockDim.x + t; e < E; e += stride)
        atomicAdd(&h[(unsigned)dst[e] >> 10], 1u);
    __syncthreads();
    if (h[t]) atomicAdd(&bucket_cnt[t], h[t]);
    if (h[t + 256]) atomicAdd(&bucket_cnt[t + 256], h[t + 256]);
}

// exclusive scan of bucket_cnt (B <= 512) -> bbase[0..B], copy into bcur
__global__ void k_bscan(const unsigned* __restrict__ bucket_cnt,
                        unsigned* __restrict__ bbase, unsigned* __restrict__ bcur, int B) {
    __shared__ unsigned s[512];
    int t = threadIdx.x;
    unsigned v = (t < B) ? bucket_cnt[t] : 0u;
    s[t] = v;
    __syncthreads();
    for (int off = 1; off < 512; off <<= 1) {
        unsigned u = (t >= off) ? s[t - off] : 0u;
        __syncthreads();
        s[t] += u;
        __syncthreads();
    }
    unsigned excl = s[t] - v;
    if (t < B) { bbase[t] = excl; bcur[t] = excl; }
    if (t == B - 1) bbase[B] = s[t];
}

// coarse scatter, block-aggregated reservation:
//   pass A: LDS histogram of this block's contiguous slice over buckets
//   reserve: one global atomicAdd per non-empty bucket (range reservation)
//   pass B: re-read slice, scatter via LDS cursors into reserved ranges.
// Each block's writes to a bucket are contiguous -> L2 line merging; global
// atomic traffic is ~nblocks per bucket, not ~degree_sum per bucket.
__global__ __launch_bounds__(256) void k_bscatter2(
        const int* __restrict__ src, const int* __restrict__ dst,
        unsigned* __restrict__ bcur, unsigned* __restrict__ pairs,
        int E, int nblocks) {
    __shared__ unsigned cnt[512];
    int t = threadIdx.x;
    int per = (E + nblocks - 1) / nblocks;
    int beg = blockIdx.x * per;
    int end = beg + per; if (end > E) end = E;
    if (beg >= E) return;
    cnt[t] = 0; cnt[t + 256] = 0;
    __syncthreads();
    for (int e = beg + t; e < end; e += 256)
        atomicAdd(&cnt[(unsigned)dst[e] >> 10], 1u);
    __syncthreads();
    unsigned c0 = cnt[t], c1 = cnt[t + 256];
    unsigned b0 = c0 ? atomicAdd(&bcur[t], c0) : 0u;
    unsigned b1 = c1 ? atomicAdd(&bcur[t + 256], c1) : 0u;
    __syncthreads();
    cnt[t] = b0; cnt[t + 256] = b1;   // LDS cursors at reserved bases
    __syncthreads();
    for (int e = beg + t; e < end; e += 256) {
        unsigned d = (unsigned)dst[e];
        unsigned pos = atomicAdd(&cnt[d >> 10], 1u);
        pairs[pos] = ((unsigned)src[e] << 10) | (d & 1023u);
    }
}

// fine pass: one block per bucket. LDS hist + scan -> row_start; scatter src
// into edges[] within the bucket's contiguous window.
__global__ __launch_bounds__(1024) void k_p2(
        const unsigned* __restrict__ pairs, const unsigned* __restrict__ bbase,
        unsigned* __restrict__ edges, unsigned* __restrict__ row_start,
        int N, int B, int E) {
    __shared__ unsigned cnt[1024], scn[1024], cur[1024];
    int t = threadIdx.x, b = blockIdx.x;
    unsigned beg = bbase[b], end = bbase[b + 1];
    cnt[t] = 0;
    __syncthreads();
    for (unsigned e = beg + t; e < end; e += 1024)
        atomicAdd(&cnt[pairs[e] & 1023u], 1u);
    __syncthreads();
    unsigned v = cnt[t];
    scn[t] = v;
    __syncthreads();
    for (int off = 1; off < 1024; off <<= 1) {
        unsigned u = (t >= off) ? scn[t - off] : 0u;
        __syncthreads();
        scn[t] += u;
        __syncthreads();
    }
    unsigned excl = scn[t] - v;
    int node = (b << 10) + t;
    if (node < N) row_start[node] = beg + excl;
    if (b == B - 1 && t == 0) row_start[N] = (unsigned)E;
    cur[t] = beg + excl;
    __syncthreads();
    for (unsigned e = beg + t; e < end; e += 1024) {
        unsigned pv = pairs[e];
        unsigned pos = atomicAdd(&cur[pv & 1023u], 1u);
        edges[pos] = pv >> 10;
    }
}

// ------- Fused layer: acc = y[n] + sum_{in-edges} y[src]; z=relu(acc+b1);
//         x=relu(z@W2+b2); p=x.l -> gacc; yout = x@W1_next -------
__global__ __launch_bounds__(256) void k_layer(
        const float* __restrict__ yin, float* __restrict__ yout,
        const unsigned* __restrict__ row_start, const unsigned* __restrict__ edges,
        const float* __restrict__ b1, const float* __restrict__ W2,
        const float* __restrict__ b2, const float* __restrict__ l,
        const float* __restrict__ W1n,
        const int* __restrict__ node_graph, float* __restrict__ gacc,
        int N, int last) {
    __shared__ float sW2[100], sW1[100], sb1[10], sb2[10], sl[10];
    int t = threadIdx.x;
    if (t < 100) sW2[t] = W2[t];
    if (!last && t >= 128 && t < 228) sW1[t - 128] = W1n[t - 128];
    if (t < 10) { sb1[t] = b1[t]; sb2[t] = b2[t]; sl[t] = l[t]; }
    __syncthreads();
    int n = blockIdx.x * 256 + t;
    bool valid = n < N;
    int nc = valid ? n : (N - 1);

    const float* yr = yin + (size_t)nc * 16;
    float4 a = *(const float4*)yr;
    float4 b = *(const float4*)(yr + 4);
    float2 c = *(const float2*)(yr + 8);
    float acc[10] = {a.x, a.y, a.z, a.w, b.x, b.y, b.z, b.w, c.x, c.y};

    unsigned beg = 0, end = 0;
    if (valid) { beg = row_start[n]; end = row_start[n + 1]; }

    unsigned e = beg;
    for (; e + 4 <= end; e += 4) {
        unsigned s0 = edges[e + 0], s1 = edges[e + 1];
        unsigned s2 = edges[e + 2], s3 = edges[e + 3];
        const float* p0 = yin + (size_t)s0 * 16;
        const float* p1 = yin + (size_t)s1 * 16;
        const float* p2 = yin + (size_t)s2 * 16;
        const float* p3 = yin + (size_t)s3 * 16;
        float4 a0 = *(const float4*)p0, b0 = *(const float4*)(p0 + 4);
        float4 a1 = *(const float4*)p1, b1v = *(const float4*)(p1 + 4);
        float4 a2 = *(const float4*)p2, b2v = *(const float4*)(p2 + 4);
        float4 a3 = *(const float4*)p3, b3 = *(const float4*)(p3 + 4);
        float2 c0 = *(const float2*)(p0 + 8), c1 = *(const float2*)(p1 + 8);
        float2 c2 = *(const float2*)(p2 + 8), c3 = *(const float2*)(p3 + 8);
        acc[0] += (a0.x + a1.x) + (a2.x + a3.x);
        acc[1] += (a0.y + a1.y) + (a2.y + a3.y);
        acc[2] += (a0.z + a1.z) + (a2.z + a3.z);
        acc[3] += (a0.w + a1.w) + (a2.w + a3.w);
        acc[4] += (b0.x + b1v.x) + (b2v.x + b3.x);
        acc[5] += (b0.y + b1v.y) + (b2v.y + b3.y);
        acc[6] += (b0.z + b1v.z) + (b2v.z + b3.z);
        acc[7] += (b0.w + b1v.w) + (b2v.w + b3.w);
        acc[8] += (c0.x + c1.x) + (c2.x + c3.x);
        acc[9] += (c0.y + c1.y) + (c2.y + c3.y);
    }
    for (; e < end; ++e) {
        unsigned s = edges[e];
        const float* pr = yin + (size_t)s * 16;
        float4 pa = *(const float4*)pr;
        float4 pb = *(const float4*)(pr + 4);
        float2 pc = *(const float2*)(pr + 8);
        acc[0] += pa.x; acc[1] += pa.y; acc[2] += pa.z; acc[3] += pa.w;
        acc[4] += pb.x; acc[5] += pb.y; acc[6] += pb.z; acc[7] += pb.w;
        acc[8] += pc.x; acc[9] += pc.y;
    }

    float z[10], x[10];
#pragma unroll
    for (int j = 0; j < 10; j++) {
        float v = acc[j] + sb1[j];
        z[j] = v > 0.f ? v : 0.f;
    }
#pragma unroll
    for (int j = 0; j < 10; j++) {
        float v = sb2[j];
#pragma unroll
        for (int k = 0; k < 10; k++) v += z[k] * sW2[k * 10 + j];
        x[j] = v > 0.f ? v : 0.f;
    }
    float p = 0.f;
#pragma unroll
    for (int j = 0; j < 10; j++) p += x[j] * sl[j];
    if (!valid) p = 0.f;
    int g = node_graph[nc];

    int g0 = __shfl(g, 0);
    if (__all(g == g0)) {
#pragma unroll
        for (int off = 32; off > 0; off >>= 1) p += __shfl_down(p, off);
        if ((t & 63) == 0) unsafeAtomicAdd(&gacc[g0], p);
    } else {
        if (valid) unsafeAtomicAdd(&gacc[g], p);
    }

    if (!last && valid) {
        float yn[10];
#pragma unroll
        for (int j = 0; j < 10; j++) {
            float v = 0.f;
#pragma unroll
            for (int k = 0; k < 10; k++) v += x[k] * sW1[k * 10 + j];
            yn[j] = v;
        }
        float* yo = yout + (size_t)n * 16;
        *(float4*)yo = make_float4(yn[0], yn[1], yn[2], yn[3]);
        *(float4*)(yo + 4) = make_float4(yn[4], yn[5], yn[6], yn[7]);
        *(float2*)(yo + 8) = make_float2(yn[8], yn[9]);
    }
}

// ---------------- Final: out[g] = sigmoid(gacc[g] / max(count,1)) ----------------
__global__ void k4_final(const float* __restrict__ gacc, const int* __restrict__ node_graph,
                         float* __restrict__ out, int N, int G) {
    int g = blockIdx.x * blockDim.x + threadIdx.x;
    if (g >= G) return;
    int lo = 0, hi = N;
    while (lo < hi) { int m = (lo + hi) >> 1; if (node_graph[m] < g) lo = m + 1; else hi = m; }
    int lo2 = lo, hi2 = N;
    while (lo2 < hi2) { int m = (lo2 + hi2) >> 1; if (node_graph[m] <= g) lo2 = m + 1; else hi2 = m; }
    float c = (float)(hi2 - lo);
    if (c < 1.f) c = 1.f;
    float s = gacc[g] / c;
    out[g] = 1.f / (1.f + __expf(-s));
}

// =================== R2 fallback CSR build (per-node atomics) ===================
__global__ void k_hist(const int* __restrict__ dst, unsigned* __restrict__ cnt, int E) {
    int stride = gridDim.x * blockDim.x;
    for (int e = blockIdx.x * blockDim.x + threadIdx.x; e < E; e += stride)
        atomicAdd(&cnt[dst[e]], 1u);
}

__global__ void k_scan1(unsigned* __restrict__ data, unsigned* __restrict__ bsums, int N) {
    __shared__ unsigned tmp[1024];
    int t = threadIdx.x;
    int idx = blockIdx.x * 1024 + t;
    unsigned v = (idx < N) ? data[idx] : 0u;
    tmp[t] = v;
    __syncthreads();
    for (int off = 1; off < 1024; off <<= 1) {
        unsigned u = (t >= off) ? tmp[t - off] : 0u;
        __syncthreads();
        tmp[t] += u;
        __syncthreads();
    }
    if (idx < N) data[idx] = tmp[t] - v;
    if (t == 1023) bsums[blockIdx.x] = tmp[1023];
}

__global__ void k_scan2(unsigned* __restrict__ bsums, int nb) {
    __shared__ unsigned tmp[1024];
    int t = threadIdx.x;
    unsigned v = (t < nb) ? bsums[t] : 0u;
    tmp[t] = v;
    __syncthreads();
    for (int off = 1; off < 1024; off <<= 1) {
        unsigned u = (t >= off) ? tmp[t - off] : 0u;
        __syncthreads();
        tmp[t] += u;
        __syncthreads();
    }
    if (t < nb) bsums[t] = tmp[t] - v;
}

__global__ void k_scan3(unsigned* __restrict__ data, const unsigned* __restrict__ bsums,
                        unsigned* __restrict__ cursor, int N, int E) {
    int n = blockIdx.x * blockDim.x + threadIdx.x;
    if (n > N) return;
    if (n == N) { data[N] = (unsigned)E; return; }
    unsigned v = data[n] + bsums[n >> 10];
    data[n] = v;
    cursor[n] = v;
}

__global__ void k_scatter(const int* __restrict__ src, const int* __restrict__ dst,
                          unsigned* __restrict__ cursor, unsigned* __restrict__ edges, int E) {
    int stride = gridDim.x * blockDim.x;
    for (int e = blockIdx.x * blockDim.x + threadIdx.x; e < E; e += stride) {
        unsigned pos = atomicAdd(&cursor[dst[e]], 1u);
        edges[pos] = (unsigned)src[e];
    }
}

extern "C" void kernel_launch(void* const* d_in, const int* in_sizes, int n_in,
                              void* d_out, int out_size, void* d_ws, size_t ws_size,
                              hipStream_t stream) {
    const float* h  = (const float*)d_in[0];
    const int* src  = (const int*)d_in[1];
    const int* dst  = (const int*)d_in[2];
    const int* ng   = (const int*)d_in[3];
    int N = in_sizes[3];
    int E = in_sizes[1];
    int G = out_size;

    const float* W1[5]; const float* b1[5]; const float* W2[5]; const float* b2[5]; const float* l[5];
    for (int i = 0; i < 5; i++) {
        W1[i] = (const float*)d_in[4 + i * 5 + 0];
        b1[i] = (const float*)d_in[4 + i * 5 + 1];
        W2[i] = (const float*)d_in[4 + i * 5 + 2];
        b2[i] = (const float*)d_in[4 + i * 5 + 3];
        l[i]  = (const float*)d_in[4 + i * 5 + 4];
    }
    float* out = (float*)d_out;

    int B = (N + 1023) >> 10;  // buckets of 1024 nodes

    // R4 layout (4B units):
    //   y0[N*16] | region2 = max(pairs[E], y1[N*16]) | edges[E] | row_start[N+1]
    //   | bucket_cnt[512] | bbase[513] | bcur[512] | gacc[G]
    size_t regAB = (size_t)N * 16;
    size_t reg2 = ((size_t)E > (size_t)N * 16) ? (size_t)E : (size_t)N * 16;
    size_t need_r4 = (regAB + reg2 + (size_t)E + (size_t)(N + 1) + 1537 + (size_t)G) * 4;

    if (ws_size >= need_r4 && B <= 512) {
        float* y0 = (float*)d_ws;
        unsigned* pairs = (unsigned*)(y0 + regAB);
        float* y1 = (float*)pairs;  // pairs dead after k_p2
        unsigned* edges = pairs + reg2;
        unsigned* row_start = edges + E;
        unsigned* bucket_cnt = row_start + (N + 1);
        unsigned* bbase = bucket_cnt + 512;
        unsigned* bcur = bbase + 513;
        float* gacc = (float*)(bcur + 512);

        hipMemsetAsync(bucket_cnt, 0, 512 * 4, stream);
        hipMemsetAsync(gacc, 0, (size_t)G * 4, stream);

        k1_hw1<16><<<(N + 255) / 256, 256, 0, stream>>>(h, W1[0], y0, N);

        k_bhist<<<2048, 256, 0, stream>>>(dst, bucket_cnt, E);
        k_bscan<<<1, 512, 0, stream>>>(bucket_cnt, bbase, bcur, B);
        int nblocks = 2048;
        k_bscatter2<<<nblocks, 256, 0, stream>>>(src, dst, bcur, pairs, E, nblocks);
        k_p2<<<B, 1024, 0, stream>>>(pairs, bbase, edges, row_start, N, B, E);

        float* ybuf[2] = {y0, y1};
        for (int i = 0; i < 5; i++) {
            k_layer<<<(N + 255) / 256, 256, 0, stream>>>(
                ybuf[i & 1], ybuf[(i + 1) & 1], row_start, edges,
                b1[i], W2[i], b2[i], l[i], i < 4 ? W1[i + 1] : nullptr,
                ng, gacc, N, i == 4 ? 1 : 0);
        }
        k4_final<<<(G + 255) / 256, 256, 0, stream>>>(gacc, ng, out, N, G);
        return;
    }

    // R2 fallback: per-node atomic CSR build
    float* y0 = (float*)d_ws;
    float* y1 = y0 + (size_t)N * 16;
    unsigned* row_start = (unsigned*)(y1 + (size_t)N * 16);
    unsigned* cursor = row_start + (N + 1);
    unsigned* bsums = cursor + N;
    unsigned* edges = bsums + 1024;
    float* gacc = (float*)(edges + E);

    hipMemsetAsync(row_start, 0, (size_t)N * 4, stream);
    hipMemsetAsync(gacc, 0, (size_t)G * 4, stream);

    k1_hw1<16><<<(N + 255) / 256, 256, 0, stream>>>(h, W1[0], y0, N);

    k_hist<<<2048, 256, 0, stream>>>(dst, row_start, E);
    int nb = (N + 1023) / 1024;
    k_scan1<<<nb, 1024, 0, stream>>>(row_start, bsums, N);
    k_scan2<<<1, 1024, 0, stream>>>(bsums, nb);
    k_scan3<<<(N + 256) / 256, 256, 0, stream>>>(row_start, bsums, cursor, N, E);
    k_scatter<<<2048, 256, 0, stream>>>(src, dst, cursor, edges, E);

    float* ybuf[2] = {y0, y1};
    for (int i = 0; i < 5; i++) {
        k_layer<<<(N + 255) / 256, 256, 0, stream>>>(
            ybuf[i & 1], ybuf[(i + 1) & 1], row_start, edges,
            b1[i], W2[i], b2[i], l[i], i < 4 ? W1[i + 1] : nullptr,
            ng, gacc, N, i == 4 ? 1 : 0);
    }
    k4_final<<<(G + 255) / 256, 256, 0, stream>>>(gacc, ng, out, N, G);
}

// Round 5
// 2721.341 us; speedup vs baseline: 2.7839x; 1.1400x over previous
//
#include <hip/hip_runtime.h>

// GIN: 5 layers, DIM=10. Identity: (x+agg)@W1 = x@W1 + segsum((x@W1)[src]).
// R5: edge-parallel aggregation (one edge per lane, wave-segmented reduction,
// zero atomics) + node-parallel MLP. CSR edges hold packed (src<<10)|dst_lo10.

#define SENTINEL 0xFFFFFFFFu

// ---------------- Layer-1: y = h @ W1_1   (h:[N,64], W1:[64,10]) ----------------
__global__ void k1_hw1(const float* __restrict__ h, const float* __restrict__ W1,
                       float* __restrict__ y, int N) {
    __shared__ float sW[640];
    for (int i = threadIdx.x; i < 640; i += blockDim.x) sW[i] = W1[i];
    __syncthreads();
    int n = blockIdx.x * blockDim.x + threadIdx.x;
    if (n >= N) return;
    const float* hr = h + (size_t)n * 64;
    float acc[10];
#pragma unroll
    for (int j = 0; j < 10; j++) acc[j] = 0.f;
#pragma unroll 4
    for (int k = 0; k < 64; k += 4) {
        float4 hv = *(const float4*)(hr + k);
#pragma unroll
        for (int j = 0; j < 10; j++) {
            acc[j] += hv.x * sW[(k + 0) * 10 + j];
            acc[j] += hv.y * sW[(k + 1) * 10 + j];
            acc[j] += hv.z * sW[(k + 2) * 10 + j];
            acc[j] += hv.w * sW[(k + 3) * 10 + j];
        }
    }
    float* yr = y + (size_t)n * 16;
#pragma unroll
    for (int j = 0; j < 10; j++) yr[j] = acc[j];
}

// =================== CSR build: two-level bucket split ===================
__global__ void k_bhist(const int* __restrict__ dst, unsigned* __restrict__ bucket_cnt,
                        int E) {
    __shared__ unsigned h[512];
    int t = threadIdx.x;
    h[t] = 0; h[t + 256] = 0;
    __syncthreads();
    int stride = gridDim.x * blockDim.x;
    for (int e = blockIdx.x * blockDim.x + t; e < E; e += stride)
        atomicAdd(&h[(unsigned)dst[e] >> 10], 1u);
    __syncthreads();
    if (h[t]) atomicAdd(&bucket_cnt[t], h[t]);
    if (h[t + 256]) atomicAdd(&bucket_cnt[t + 256], h[t + 256]);
}

__global__ void k_bscan(const unsigned* __restrict__ bucket_cnt,
                        unsigned* __restrict__ bbase, unsigned* __restrict__ bcur, int B) {
    __shared__ unsigned s[512];
    int t = threadIdx.x;
    unsigned v = (t < B) ? bucket_cnt[t] : 0u;
    s[t] = v;
    __syncthreads();
    for (int off = 1; off < 512; off <<= 1) {
        unsigned u = (t >= off) ? s[t - off] : 0u;
        __syncthreads();
        s[t] += u;
        __syncthreads();
    }
    unsigned excl = s[t] - v;
    if (t < B) { bbase[t] = excl; bcur[t] = excl; }
    if (t == B - 1) bbase[B] = s[t];
}

__global__ __launch_bounds__(256) void k_bscatter2(
        const int* __restrict__ src, const int* __restrict__ dst,
        unsigned* __restrict__ bcur, unsigned* __restrict__ pairs,
        int E, int nblocks) {
    __shared__ unsigned cnt[512];
    int t = threadIdx.x;
    int per = (E + nblocks - 1) / nblocks;
    int beg = blockIdx.x * per;
    int end = beg + per; if (end > E) end = E;
    if (beg >= E) return;
    cnt[t] = 0; cnt[t + 256] = 0;
    __syncthreads();
    for (int e = beg + t; e < end; e += 256)
        atomicAdd(&cnt[(unsigned)dst[e] >> 10], 1u);
    __syncthreads();
    unsigned c0 = cnt[t], c1 = cnt[t + 256];
    unsigned b0 = c0 ? atomicAdd(&bcur[t], c0) : 0u;
    unsigned b1 = c1 ? atomicAdd(&bcur[t + 256], c1) : 0u;
    __syncthreads();
    cnt[t] = b0; cnt[t + 256] = b1;
    __syncthreads();
    for (int e = beg + t; e < end; e += 256) {
        unsigned d = (unsigned)dst[e];
        unsigned pos = atomicAdd(&cnt[d >> 10], 1u);
        pairs[pos] = ((unsigned)src[e] << 10) | (d & 1023u);
    }
}

// fine pass: one block per bucket; emits row_start and dst-sorted edge array.
// packed=1 -> store full (src<<10)|dst_lo; packed=0 -> store src only.
__global__ __launch_bounds__(1024) void k_p2(
        const unsigned* __restrict__ pairs, const unsigned* __restrict__ bbase,
        unsigned* __restrict__ edges, unsigned* __restrict__ row_start,
        int N, int B, int E, int packed) {
    __shared__ unsigned cnt[1024], scn[1024], cur[1024];
    int t = threadIdx.x, b = blockIdx.x;
    unsigned beg = bbase[b], end = bbase[b + 1];
    cnt[t] = 0;
    __syncthreads();
    for (unsigned e = beg + t; e < end; e += 1024)
        atomicAdd(&cnt[pairs[e] & 1023u], 1u);
    __syncthreads();
    unsigned v = cnt[t];
    scn[t] = v;
    __syncthreads();
    for (int off = 1; off < 1024; off <<= 1) {
        unsigned u = (t >= off) ? scn[t - off] : 0u;
        __syncthreads();
        scn[t] += u;
        __syncthreads();
    }
    unsigned excl = scn[t] - v;
    int node = (b << 10) + t;
    if (node < N) row_start[node] = beg + excl;
    if (b == B - 1 && t == 0) row_start[N] = (unsigned)E;
    cur[t] = beg + excl;
    __syncthreads();
    for (unsigned e = beg + t; e < end; e += 1024) {
        unsigned pv = pairs[e];
        unsigned pos = atomicAdd(&cur[pv & 1023u], 1u);
        edges[pos] = packed ? pv : (pv >> 10);
    }
}

// =================== R5 hot phase ===================
// kA: one edge per lane. Gather row, segmented wave reduction, plain stores.
__global__ __launch_bounds__(256) void kA_agg(
        const float* __restrict__ yin, const unsigned* __restrict__ epk,
        const unsigned* __restrict__ bbase,
        float* __restrict__ agg, float* __restrict__ carry_val,
        unsigned* __restrict__ carry_dst, int E, int B, int W) {
    __shared__ unsigned sb[513];
    for (int i = threadIdx.x; i < B + 1; i += 256) sb[i] = bbase[i];
    __syncthreads();
    int lane = threadIdx.x & 63;
    int w = blockIdx.x * 4 + (threadIdx.x >> 6);
    int e = (w << 6) + lane;
    bool v = e < E;
    float acc[10];
    unsigned dst;
    if (v) {
        unsigned pv = epk[e];
        unsigned s = pv >> 10;
        const float* pr = yin + (size_t)s * 16;
        float4 a = *(const float4*)pr;
        float4 b = *(const float4*)(pr + 4);
        float2 c = *(const float2*)(pr + 8);
        // bucket of e: largest b with sb[b] <= e
        int lo = 0, hi = B - 1;
        while (lo < hi) { int m = (lo + hi + 1) >> 1; if (sb[m] <= (unsigned)e) lo = m; else hi = m - 1; }
        dst = ((unsigned)lo << 10) | (pv & 1023u);
        acc[0] = a.x; acc[1] = a.y; acc[2] = a.z; acc[3] = a.w;
        acc[4] = b.x; acc[5] = b.y; acc[6] = b.z; acc[7] = b.w;
        acc[8] = c.x; acc[9] = c.y;
    } else {
        dst = SENTINEL;
#pragma unroll
        for (int j = 0; j < 10; j++) acc[j] = 0.f;
    }
    // segmented inclusive scan over sorted keys
#pragma unroll
    for (int off = 1; off < 64; off <<= 1) {
        unsigned od = __shfl_up(dst, off);
        float tv[10];
#pragma unroll
        for (int j = 0; j < 10; j++) tv[j] = __shfl_up(acc[j], off);
        bool take = (lane >= off) && (od == dst);
#pragma unroll
        for (int j = 0; j < 10; j++) acc[j] = take ? acc[j] + tv[j] : acc[j];
    }
    unsigned dn = __shfl_down(dst, 1);
    bool is_end = (lane < 63) && (dst != dn);
    if (v && is_end) {
        float* ar = agg + (size_t)dst * 16;
        *(float4*)ar = make_float4(acc[0], acc[1], acc[2], acc[3]);
        *(float4*)(ar + 4) = make_float4(acc[4], acc[5], acc[6], acc[7]);
        *(float2*)(ar + 8) = make_float2(acc[8], acc[9]);
    }
    if (lane == 63 && w < W) {
        carry_dst[w] = dst;
        float* cr = carry_val + (size_t)w * 16;
        *(float4*)cr = make_float4(acc[0], acc[1], acc[2], acc[3]);
        *(float4*)(cr + 4) = make_float4(acc[4], acc[5], acc[6], acc[7]);
        *(float2*)(cr + 8) = make_float2(acc[8], acc[9]);
    }
}

// kB: node-parallel MLP. Reconstructs agg from interior store + wave carries
// (validity is pure row_start arithmetic -> no zero-init, no atomics).
__global__ __launch_bounds__(256) void kB_node(
        const float* __restrict__ yin, float* __restrict__ yout,
        const float* __restrict__ agg,
        const unsigned* __restrict__ row_start,
        const unsigned* __restrict__ carry_dst, const float* __restrict__ carry_val,
        const float* __restrict__ b1, const float* __restrict__ W2,
        const float* __restrict__ b2, const float* __restrict__ l,
        const float* __restrict__ W1n,
        const int* __restrict__ node_graph, float* __restrict__ gacc,
        int N, int last) {
    __shared__ float sW2[100], sW1[100], sb1[10], sb2[10], sl[10];
    int t = threadIdx.x;
    if (t < 100) sW2[t] = W2[t];
    if (!last && t >= 128 && t < 228) sW1[t - 128] = W1n[t - 128];
    if (t < 10) { sb1[t] = b1[t]; sb2[t] = b2[t]; sl[t] = l[t]; }
    __syncthreads();
    int n = blockIdx.x * 256 + t;
    bool valid = n < N;
    int nc = valid ? n : (N - 1);
    const float* yr = yin + (size_t)nc * 16;
    float4 a = *(const float4*)yr;
    float4 b = *(const float4*)(yr + 4);
    float2 c = *(const float2*)(yr + 8);
    float acc[10] = {a.x, a.y, a.z, a.w, b.x, b.y, b.z, b.w, c.x, c.y};

    if (valid) {
        unsigned rs0 = row_start[n], rs1 = row_start[n + 1];
        if (rs1 > rs0) {
            unsigned le = rs1 - 1;
            if ((le & 63u) != 63u) {
                const float* ar = agg + (size_t)n * 16;
                float4 pa = *(const float4*)ar;
                float4 pb = *(const float4*)(ar + 4);
                float2 pc = *(const float2*)(ar + 8);
                acc[0] += pa.x; acc[1] += pa.y; acc[2] += pa.z; acc[3] += pa.w;
                acc[4] += pb.x; acc[5] += pb.y; acc[6] += pb.z; acc[7] += pb.w;
                acc[8] += pc.x; acc[9] += pc.y;
            }
            unsigned w0 = rs0 >> 6, w1 = le >> 6;
            for (unsigned w = w0; w <= w1; ++w) {
                if (carry_dst[w] == (unsigned)n) {
                    const float* cr = carry_val + (size_t)w * 16;
                    float4 pa = *(const float4*)cr;
                    float4 pb = *(const float4*)(cr + 4);
                    float2 pc = *(const float2*)(cr + 8);
                    acc[0] += pa.x; acc[1] += pa.y; acc[2] += pa.z; acc[3] += pa.w;
                    acc[4] += pb.x; acc[5] += pb.y; acc[6] += pb.z; acc[7] += pb.w;
                    acc[8] += pc.x; acc[9] += pc.y;
                }
            }
        }
    }

    float z[10], x[10];
#pragma unroll
    for (int j = 0; j < 10; j++) {
        float v = acc[j] + sb1[j];
        z[j] = v > 0.f ? v : 0.f;
    }
#pragma unroll
    for (int j = 0; j < 10; j++) {
        float v = sb2[j];
#pragma unroll
        for (int k = 0; k < 10; k++) v += z[k] * sW2[k * 10 + j];
        x[j] = v > 0.f ? v : 0.f;
    }
    float p = 0.f;
#pragma unroll
    for (int j = 0; j < 10; j++) p += x[j] * sl[j];
    if (!valid) p = 0.f;
    int g = node_graph[nc];

    int g0 = __shfl(g, 0);
    if (__all(g == g0)) {
#pragma unroll
        for (int off = 32; off > 0; off >>= 1) p += __shfl_down(p, off);
        if ((t & 63) == 0) unsafeAtomicAdd(&gacc[g0], p);
    } else {
        if (valid) unsafeAtomicAdd(&gacc[g], p);
    }

    if (!last && valid) {
        float yn[10];
#pragma unroll
        for (int j = 0; j < 10; j++) {
            float v = 0.f;
#pragma unroll
            for (int k = 0; k < 10; k++) v += x[k] * sW1[k * 10 + j];
            yn[j] = v;
        }
        float* yo = yout + (size_t)n * 16;
        *(float4*)yo = make_float4(yn[0], yn[1], yn[2], yn[3]);
        *(float4*)(yo + 4) = make_float4(yn[4], yn[5], yn[6], yn[7]);
        *(float2*)(yo + 8) = make_float2(yn[8], yn[9]);
    }
}

// ---------------- Final: out[g] = sigmoid(gacc[g] / max(count,1)) ----------------
__global__ void k4_final(const float* __restrict__ gacc, const int* __restrict__ node_graph,
                         float* __restrict__ out, int N, int G) {
    int g = blockIdx.x * blockDim.x + threadIdx.x;
    if (g >= G) return;
    int lo = 0, hi = N;
    while (lo < hi) { int m = (lo + hi) >> 1; if (node_graph[m] < g) lo = m + 1; else hi = m; }
    int lo2 = lo, hi2 = N;
    while (lo2 < hi2) { int m = (lo2 + hi2) >> 1; if (node_graph[m] <= g) lo2 = m + 1; else hi2 = m; }
    float c = (float)(hi2 - lo);
    if (c < 1.f) c = 1.f;
    float s = gacc[g] / c;
    out[g] = 1.f / (1.f + __expf(-s));
}

// ============ R4 fallback fused layer (src-only edges) ============
__global__ __launch_bounds__(256) void k_layer(
        const float* __restrict__ yin, float* __restrict__ yout,
        const unsigned* __restrict__ row_start, const unsigned* __restrict__ edges,
        const float* __restrict__ b1, const float* __restrict__ W2,
        const float* __restrict__ b2, const float* __restrict__ l,
        const float* __restrict__ W1n,
        const int* __restrict__ node_graph, float* __restrict__ gacc,
        int N, int last) {
    __shared__ float sW2[100], sW1[100], sb1[10], sb2[10], sl[10];
    int t = threadIdx.x;
    if (t < 100) sW2[t] = W2[t];
    if (!last && t >= 128 && t < 228) sW1[t - 128] = W1n[t - 128];
    if (t < 10) { sb1[t] = b1[t]; sb2[t] = b2[t]; sl[t] = l[t]; }
    __syncthreads();
    int n = blockIdx.x * 256 + t;
    bool valid = n < N;
    int nc = valid ? n : (N - 1);
    const float* yr = yin + (size_t)nc * 16;
    float4 a = *(const float4*)yr;
    float4 b = *(const float4*)(yr + 4);
    float2 c = *(const float2*)(yr + 8);
    float acc[10] = {a.x, a.y, a.z, a.w, b.x, b.y, b.z, b.w, c.x, c.y};
    unsigned beg = 0, end = 0;
    if (valid) { beg = row_start[n]; end = row_start[n + 1]; }
    for (unsigned e = beg; e < end; ++e) {
        unsigned s = edges[e];
        const float* pr = yin + (size_t)s * 16;
        float4 pa = *(const float4*)pr;
        float4 pb = *(const float4*)(pr + 4);
        float2 pc = *(const float2*)(pr + 8);
        acc[0] += pa.x; acc[1] += pa.y; acc[2] += pa.z; acc[3] += pa.w;
        acc[4] += pb.x; acc[5] += pb.y; acc[6] += pb.z; acc[7] += pb.w;
        acc[8] += pc.x; acc[9] += pc.y;
    }
    float z[10], x[10];
#pragma unroll
    for (int j = 0; j < 10; j++) {
        float v = acc[j] + sb1[j];
        z[j] = v > 0.f ? v : 0.f;
    }
#pragma unroll
    for (int j = 0; j < 10; j++) {
        float v = sb2[j];
#pragma unroll
        for (int k = 0; k < 10; k++) v += z[k] * sW2[k * 10 + j];
        x[j] = v > 0.f ? v : 0.f;
    }
    float p = 0.f;
#pragma unroll
    for (int j = 0; j < 10; j++) p += x[j] * sl[j];
    if (!valid) p = 0.f;
    int g = node_graph[nc];
    int g0 = __shfl(g, 0);
    if (__all(g == g0)) {
#pragma unroll
        for (int off = 32; off > 0; off >>= 1) p += __shfl_down(p, off);
        if ((t & 63) == 0) unsafeAtomicAdd(&gacc[g0], p);
    } else {
        if (valid) unsafeAtomicAdd(&gacc[g], p);
    }
    if (!last && valid) {
        float yn[10];
#pragma unroll
        for (int j = 0; j < 10; j++) {
            float v = 0.f;
#pragma unroll
            for (int k = 0; k < 10; k++) v += x[k] * sW1[k * 10 + j];
            yn[j] = v;
        }
        float* yo = yout + (size_t)n * 16;
        *(float4*)yo = make_float4(yn[0], yn[1], yn[2], yn[3]);
        *(float4*)(yo + 4) = make_float4(yn[4], yn[5], yn[6], yn[7]);
        *(float2*)(yo + 8) = make_float2(yn[8], yn[9]);
    }
}

extern "C" void kernel_launch(void* const* d_in, const int* in_sizes, int n_in,
                              void* d_out, int out_size, void* d_ws, size_t ws_size,
                              hipStream_t stream) {
    const float* h  = (const float*)d_in[0];
    const int* src  = (const int*)d_in[1];
    const int* dst  = (const int*)d_in[2];
    const int* ng   = (const int*)d_in[3];
    int N = in_sizes[3];
    int E = in_sizes[1];
    int G = out_size;

    const float* W1[5]; const float* b1[5]; const float* W2[5]; const float* b2[5]; const float* l[5];
    for (int i = 0; i < 5; i++) {
        W1[i] = (const float*)d_in[4 + i * 5 + 0];
        b1[i] = (const float*)d_in[4 + i * 5 + 1];
        W2[i] = (const float*)d_in[4 + i * 5 + 2];
        b2[i] = (const float*)d_in[4 + i * 5 + 3];
        l[i]  = (const float*)d_in[4 + i * 5 + 4];
    }
    float* out = (float*)d_out;

    int B = (N + 1023) >> 10;
    int W = (E + 63) >> 6;          // waves in kA
    size_t regAB = (size_t)N * 16;
    size_t reg2 = ((size_t)E > regAB) ? (size_t)E : regAB;

    // R5 layout: y0 | reg2(pairs->y1) | edges | row_start[N+1] | agg[N*16]
    //            | carry_val[W*16] | carry_dst[W] | bucket_cnt 512 | bbase 513
    //            | bcur 512 | gacc[G]
    size_t need_r5 = (regAB + reg2 + (size_t)E + (size_t)(N + 1) + regAB
                      + (size_t)W * 17 + 1537 + (size_t)G) * 4;
    size_t need_r4 = (regAB + reg2 + (size_t)E + (size_t)(N + 1) + 1537 + (size_t)G) * 4;

    if (ws_size >= need_r5 && B <= 512) {
        float* y0 = (float*)d_ws;
        unsigned* pairs = (unsigned*)(y0 + regAB);
        float* y1 = (float*)pairs;
        unsigned* edges = pairs + reg2;
        unsigned* row_start = edges + E;
        float* agg = (float*)(row_start + (N + 1));
        float* carry_val = agg + regAB;
        unsigned* carry_dst = (unsigned*)(carry_val + (size_t)W * 16);
        unsigned* bucket_cnt = carry_dst + W;
        unsigned* bbase = bucket_cnt + 512;
        unsigned* bcur = bbase + 513;
        float* gacc = (float*)(bcur + 512);

        hipMemsetAsync(bucket_cnt, 0, 512 * 4, stream);
        hipMemsetAsync(gacc, 0, (size_t)G * 4, stream);

        k1_hw1<<<(N + 255) / 256, 256, 0, stream>>>(h, W1[0], y0, N);

        k_bhist<<<2048, 256, 0, stream>>>(dst, bucket_cnt, E);
        k_bscan<<<1, 512, 0, stream>>>(bucket_cnt, bbase, bcur, B);
        k_bscatter2<<<2048, 256, 0, stream>>>(src, dst, bcur, pairs, E, 2048);
        k_p2<<<B, 1024, 0, stream>>>(pairs, bbase, edges, row_start, N, B, E, 1);

        float* ybuf[2] = {y0, y1};
        int ablocks = (W + 3) / 4;
        for (int i = 0; i < 5; i++) {
            kA_agg<<<ablocks, 256, 0, stream>>>(
                ybuf[i & 1], edges, bbase, agg, carry_val, carry_dst, E, B, W);
            kB_node<<<(N + 255) / 256, 256, 0, stream>>>(
                ybuf[i & 1], ybuf[(i + 1) & 1], agg, row_start, carry_dst, carry_val,
                b1[i], W2[i], b2[i], l[i], i < 4 ? W1[i + 1] : nullptr,
                ng, gacc, N, i == 4 ? 1 : 0);
        }
        k4_final<<<(G + 255) / 256, 256, 0, stream>>>(gacc, ng, out, N, G);
        return;
    }

    // R4 fallback: bucketed build + fused node-parallel layer (src-only edges)
    if (ws_size >= need_r4 && B <= 512) {
        float* y0 = (float*)d_ws;
        unsigned* pairs = (unsigned*)(y0 + regAB);
        float* y1 = (float*)pairs;
        unsigned* edges = pairs + reg2;
        unsigned* row_start = edges + E;
        unsigned* bucket_cnt = row_start + (N + 1);
        unsigned* bbase = bucket_cnt + 512;
        unsigned* bcur = bbase + 513;
        float* gacc = (float*)(bcur + 512);

        hipMemsetAsync(bucket_cnt, 0, 512 * 4, stream);
        hipMemsetAsync(gacc, 0, (size_t)G * 4, stream);

        k1_hw1<<<(N + 255) / 256, 256, 0, stream>>>(h, W1[0], y0, N);
        k_bhist<<<2048, 256, 0, stream>>>(dst, bucket_cnt, E);
        k_bscan<<<1, 512, 0, stream>>>(bucket_cnt, bbase, bcur, B);
        k_bscatter2<<<2048, 256, 0, stream>>>(src, dst, bcur, pairs, E, 2048);
        k_p2<<<B, 1024, 0, stream>>>(pairs, bbase, edges, row_start, N, B, E, 0);

        float* ybuf[2] = {y0, y1};
        for (int i = 0; i < 5; i++) {
            k_layer<<<(N + 255) / 256, 256, 0, stream>>>(
                ybuf[i & 1], ybuf[(i + 1) & 1], row_start, edges,
                b1[i], W2[i], b2[i], l[i], i < 4 ? W1[i + 1] : nullptr,
                ng, gacc, N, i == 4 ? 1 : 0);
        }
        k4_final<<<(G + 255) / 256, 256, 0, stream>>>(gacc, ng, out, N, G);
    }
}

// Round 6
// 2347.899 us; speedup vs baseline: 3.2267x; 1.1591x over previous
//
#include <hip/hip_runtime.h>

// GIN: 5 layers, DIM=10. Identity: (x+agg)@W1 = x@W1 + segsum((x@W1)[src]).
// R6: y stored as bf16 rows (16 halves = 32B) -> halves gather working set;
// k_bscatter2 retuned to 256x1024 (resident write frontier fits L2).
// Edge-parallel aggregation (wave-segmented scan, zero atomics) + node MLP.

#define SENTINEL 0xFFFFFFFFu

__device__ __forceinline__ unsigned short f2bf(float f) {
    unsigned b = __float_as_uint(f);
    b += 0x7fffu + ((b >> 16) & 1u);   // round-to-nearest-even
    return (unsigned short)(b >> 16);
}
__device__ __forceinline__ float bflo(unsigned u) { return __uint_as_float(u << 16); }
__device__ __forceinline__ float bfhi(unsigned u) { return __uint_as_float(u & 0xffff0000u); }

// ---------------- Layer-1: y = h @ W1_1 (bf16 rows, 8 uints/row) ----------------
__global__ void k1_hw1_bf16(const float* __restrict__ h, const float* __restrict__ W1,
                            unsigned* __restrict__ y, int N) {
    __shared__ float sW[640];
    for (int i = threadIdx.x; i < 640; i += blockDim.x) sW[i] = W1[i];
    __syncthreads();
    int n = blockIdx.x * blockDim.x + threadIdx.x;
    if (n >= N) return;
    const float* hr = h + (size_t)n * 64;
    float acc[10];
#pragma unroll
    for (int j = 0; j < 10; j++) acc[j] = 0.f;
#pragma unroll 4
    for (int k = 0; k < 64; k += 4) {
        float4 hv = *(const float4*)(hr + k);
#pragma unroll
        for (int j = 0; j < 10; j++) {
            acc[j] += hv.x * sW[(k + 0) * 10 + j];
            acc[j] += hv.y * sW[(k + 1) * 10 + j];
            acc[j] += hv.z * sW[(k + 2) * 10 + j];
            acc[j] += hv.w * sW[(k + 3) * 10 + j];
        }
    }
    unsigned r0 = (unsigned)f2bf(acc[0]) | ((unsigned)f2bf(acc[1]) << 16);
    unsigned r1 = (unsigned)f2bf(acc[2]) | ((unsigned)f2bf(acc[3]) << 16);
    unsigned r2 = (unsigned)f2bf(acc[4]) | ((unsigned)f2bf(acc[5]) << 16);
    unsigned r3 = (unsigned)f2bf(acc[6]) | ((unsigned)f2bf(acc[7]) << 16);
    unsigned r4 = (unsigned)f2bf(acc[8]) | ((unsigned)f2bf(acc[9]) << 16);
    unsigned* yr = y + (size_t)n * 8;
    *(uint4*)yr = make_uint4(r0, r1, r2, r3);
    yr[4] = r4;
}

// f32 variant for the fallback path (16-float rows)
__global__ void k1_hw1_f32(const float* __restrict__ h, const float* __restrict__ W1,
                           float* __restrict__ y, int N) {
    __shared__ float sW[640];
    for (int i = threadIdx.x; i < 640; i += blockDim.x) sW[i] = W1[i];
    __syncthreads();
    int n = blockIdx.x * blockDim.x + threadIdx.x;
    if (n >= N) return;
    const float* hr = h + (size_t)n * 64;
    float acc[10];
#pragma unroll
    for (int j = 0; j < 10; j++) acc[j] = 0.f;
#pragma unroll 4
    for (int k = 0; k < 64; k += 4) {
        float4 hv = *(const float4*)(hr + k);
#pragma unroll
        for (int j = 0; j < 10; j++) {
            acc[j] += hv.x * sW[(k + 0) * 10 + j];
            acc[j] += hv.y * sW[(k + 1) * 10 + j];
            acc[j] += hv.z * sW[(k + 2) * 10 + j];
            acc[j] += hv.w * sW[(k + 3) * 10 + j];
        }
    }
    float* yr = y + (size_t)n * 16;
#pragma unroll
    for (int j = 0; j < 10; j++) yr[j] = acc[j];
}

// =================== CSR build: two-level bucket split ===================
__global__ void k_bhist(const int* __restrict__ dst, unsigned* __restrict__ bucket_cnt,
                        int E) {
    __shared__ unsigned h[512];
    int t = threadIdx.x;
    h[t] = 0; h[t + 256] = 0;
    __syncthreads();
    int stride = gridDim.x * blockDim.x;
    for (int e = blockIdx.x * blockDim.x + t; e < E; e += stride)
        atomicAdd(&h[(unsigned)dst[e] >> 10], 1u);
    __syncthreads();
    if (h[t]) atomicAdd(&bucket_cnt[t], h[t]);
    if (h[t + 256]) atomicAdd(&bucket_cnt[t + 256], h[t + 256]);
}

__global__ void k_bscan(const unsigned* __restrict__ bucket_cnt,
                        unsigned* __restrict__ bbase, unsigned* __restrict__ bcur, int B) {
    __shared__ unsigned s[512];
    int t = threadIdx.x;
    unsigned v = (t < B) ? bucket_cnt[t] : 0u;
    s[t] = v;
    __syncthreads();
    for (int off = 1; off < 512; off <<= 1) {
        unsigned u = (t >= off) ? s[t - off] : 0u;
        __syncthreads();
        s[t] += u;
        __syncthreads();
    }
    unsigned excl = s[t] - v;
    if (t < B) { bbase[t] = excl; bcur[t] = excl; }
    if (t == B - 1) bbase[B] = s[t];
}

// coarse scatter, block-aggregated reservation. 1024 threads, few blocks so the
// per-XCD resident write frontier (~blocks/XCD * 489 lines) fits in 4MB L2.
__global__ __launch_bounds__(1024) void k_bscatter2(
        const int* __restrict__ src, const int* __restrict__ dst,
        unsigned* __restrict__ bcur, unsigned* __restrict__ pairs,
        int E, int nblocks) {
    __shared__ unsigned cnt[512];
    int t = threadIdx.x;
    int per = (E + nblocks - 1) / nblocks;
    int beg = blockIdx.x * per;
    int end = beg + per; if (end > E) end = E;
    if (beg >= E) return;
    if (t < 512) cnt[t] = 0;
    __syncthreads();
    for (int e = beg + t; e < end; e += 1024)
        atomicAdd(&cnt[(unsigned)dst[e] >> 10], 1u);
    __syncthreads();
    unsigned c = 0, base = 0;
    if (t < 512) { c = cnt[t]; if (c) base = atomicAdd(&bcur[t], c); }
    __syncthreads();
    if (t < 512) cnt[t] = base;
    __syncthreads();
    for (int e = beg + t; e < end; e += 1024) {
        unsigned d = (unsigned)dst[e];
        unsigned pos = atomicAdd(&cnt[d >> 10], 1u);
        pairs[pos] = ((unsigned)src[e] << 10) | (d & 1023u);
    }
}

// fine pass: one block per bucket; emits row_start and dst-sorted edge array.
__global__ __launch_bounds__(1024) void k_p2(
        const unsigned* __restrict__ pairs, const unsigned* __restrict__ bbase,
        unsigned* __restrict__ edges, unsigned* __restrict__ row_start,
        int N, int B, int E, int packed) {
    __shared__ unsigned cnt[1024], scn[1024], cur[1024];
    int t = threadIdx.x, b = blockIdx.x;
    unsigned beg = bbase[b], end = bbase[b + 1];
    cnt[t] = 0;
    __syncthreads();
    for (unsigned e = beg + t; e < end; e += 1024)
        atomicAdd(&cnt[pairs[e] & 1023u], 1u);
    __syncthreads();
    unsigned v = cnt[t];
    scn[t] = v;
    __syncthreads();
    for (int off = 1; off < 1024; off <<= 1) {
        unsigned u = (t >= off) ? scn[t - off] : 0u;
        __syncthreads();
        scn[t] += u;
        __syncthreads();
    }
    unsigned excl = scn[t] - v;
    int node = (b << 10) + t;
    if (node < N) row_start[node] = beg + excl;
    if (b == B - 1 && t == 0) row_start[N] = (unsigned)E;
    cur[t] = beg + excl;
    __syncthreads();
    for (unsigned e = beg + t; e < end; e += 1024) {
        unsigned pv = pairs[e];
        unsigned pos = atomicAdd(&cur[pv & 1023u], 1u);
        edges[pos] = packed ? pv : (pv >> 10);
    }
}

// =================== hot phase ===================
// kA: one edge per lane; bf16 row gather (2 loads); segmented wave reduction.
__global__ __launch_bounds__(256) void kA_agg(
        const unsigned* __restrict__ yin, const unsigned* __restrict__ epk,
        const unsigned* __restrict__ bbase,
        float* __restrict__ agg, float* __restrict__ carry_val,
        unsigned* __restrict__ carry_dst, int E, int B, int W) {
    __shared__ unsigned sb[513];
    for (int i = threadIdx.x; i < B + 1; i += 256) sb[i] = bbase[i];
    __syncthreads();
    int lane = threadIdx.x & 63;
    int w = blockIdx.x * 4 + (threadIdx.x >> 6);
    int e = (w << 6) + lane;
    bool v = e < E;
    float acc[10];
    unsigned dst;
    if (v) {
        unsigned pv = epk[e];
        unsigned s = pv >> 10;
        const unsigned* pr = yin + (size_t)s * 8;
        uint4 q = *(const uint4*)pr;
        unsigned q4 = pr[4];
        int lo = 0, hi = B - 1;
        while (lo < hi) { int m = (lo + hi + 1) >> 1; if (sb[m] <= (unsigned)e) lo = m; else hi = m - 1; }
        dst = ((unsigned)lo << 10) | (pv & 1023u);
        acc[0] = bflo(q.x); acc[1] = bfhi(q.x);
        acc[2] = bflo(q.y); acc[3] = bfhi(q.y);
        acc[4] = bflo(q.z); acc[5] = bfhi(q.z);
        acc[6] = bflo(q.w); acc[7] = bfhi(q.w);
        acc[8] = bflo(q4);  acc[9] = bfhi(q4);
    } else {
        dst = SENTINEL;
#pragma unroll
        for (int j = 0; j < 10; j++) acc[j] = 0.f;
    }
#pragma unroll
    for (int off = 1; off < 64; off <<= 1) {
        unsigned od = __shfl_up(dst, off);
        float tv[10];
#pragma unroll
        for (int j = 0; j < 10; j++) tv[j] = __shfl_up(acc[j], off);
        bool take = (lane >= off) && (od == dst);
#pragma unroll
        for (int j = 0; j < 10; j++) acc[j] = take ? acc[j] + tv[j] : acc[j];
    }
    unsigned dn = __shfl_down(dst, 1);
    bool is_end = (lane < 63) && (dst != dn);
    if (v && is_end) {
        float* ar = agg + (size_t)dst * 16;
        *(float4*)ar = make_float4(acc[0], acc[1], acc[2], acc[3]);
        *(float4*)(ar + 4) = make_float4(acc[4], acc[5], acc[6], acc[7]);
        *(float2*)(ar + 8) = make_float2(acc[8], acc[9]);
    }
    if (lane == 63 && w < W) {
        carry_dst[w] = dst;
        float* cr = carry_val + (size_t)w * 16;
        *(float4*)cr = make_float4(acc[0], acc[1], acc[2], acc[3]);
        *(float4*)(cr + 4) = make_float4(acc[4], acc[5], acc[6], acc[7]);
        *(float2*)(cr + 8) = make_float2(acc[8], acc[9]);
    }
}

// kB: node-parallel MLP; reconstructs agg from interior store + wave carries.
__global__ __launch_bounds__(256) void kB_node(
        const unsigned* __restrict__ yin, unsigned* __restrict__ yout,
        const float* __restrict__ agg,
        const unsigned* __restrict__ row_start,
        const unsigned* __restrict__ carry_dst, const float* __restrict__ carry_val,
        const float* __restrict__ b1, const float* __restrict__ W2,
        const float* __restrict__ b2, const float* __restrict__ l,
        const float* __restrict__ W1n,
        const int* __restrict__ node_graph, float* __restrict__ gacc,
        int N, int last) {
    __shared__ float sW2[100], sW1[100], sb1[10], sb2[10], sl[10];
    int t = threadIdx.x;
    if (t < 100) sW2[t] = W2[t];
    if (!last && t >= 128 && t < 228) sW1[t - 128] = W1n[t - 128];
    if (t < 10) { sb1[t] = b1[t]; sb2[t] = b2[t]; sl[t] = l[t]; }
    __syncthreads();
    int n = blockIdx.x * 256 + t;
    bool valid = n < N;
    int nc = valid ? n : (N - 1);
    const unsigned* yr = yin + (size_t)nc * 8;
    uint4 q = *(const uint4*)yr;
    unsigned q4 = yr[4];
    float acc[10] = {bflo(q.x), bfhi(q.x), bflo(q.y), bfhi(q.y),
                     bflo(q.z), bfhi(q.z), bflo(q.w), bfhi(q.w),
                     bflo(q4),  bfhi(q4)};

    if (valid) {
        unsigned rs0 = row_start[n], rs1 = row_start[n + 1];
        if (rs1 > rs0) {
            unsigned le = rs1 - 1;
            if ((le & 63u) != 63u) {
                const float* ar = agg + (size_t)n * 16;
                float4 pa = *(const float4*)ar;
                float4 pb = *(const float4*)(ar + 4);
                float2 pc = *(const float2*)(ar + 8);
                acc[0] += pa.x; acc[1] += pa.y; acc[2] += pa.z; acc[3] += pa.w;
                acc[4] += pb.x; acc[5] += pb.y; acc[6] += pb.z; acc[7] += pb.w;
                acc[8] += pc.x; acc[9] += pc.y;
            }
            unsigned w0 = rs0 >> 6, w1 = le >> 6;
            for (unsigned w = w0; w <= w1; ++w) {
                if (carry_dst[w] == (unsigned)n) {
                    const float* cr = carry_val + (size_t)w * 16;
                    float4 pa = *(const float4*)cr;
                    float4 pb = *(const float4*)(cr + 4);
                    float2 pc = *(const float2*)(cr + 8);
                    acc[0] += pa.x; acc[1] += pa.y; acc[2] += pa.z; acc[3] += pa.w;
                    acc[4] += pb.x; acc[5] += pb.y; acc[6] += pb.z; acc[7] += pb.w;
                    acc[8] += pc.x; acc[9] += pc.y;
                }
            }
        }
    }

    float z[10], x[10];
#pragma unroll
    for (int j = 0; j < 10; j++) {
        float v = acc[j] + sb1[j];
        z[j] = v > 0.f ? v : 0.f;
    }
#pragma unroll
    for (int j = 0; j < 10; j++) {
        float v = sb2[j];
#pragma unroll
        for (int k = 0; k < 10; k++) v += z[k] * sW2[k * 10 + j];
        x[j] = v > 0.f ? v : 0.f;
    }
    float p = 0.f;
#pragma unroll
    for (int j = 0; j < 10; j++) p += x[j] * sl[j];
    if (!valid) p = 0.f;
    int g = node_graph[nc];

    int g0 = __shfl(g, 0);
    if (__all(g == g0)) {
#pragma unroll
        for (int off = 32; off > 0; off >>= 1) p += __shfl_down(p, off);
        if ((t & 63) == 0) unsafeAtomicAdd(&gacc[g0], p);
    } else {
        if (valid) unsafeAtomicAdd(&gacc[g], p);
    }

    if (!last && valid) {
        float yn[10];
#pragma unroll
        for (int j = 0; j < 10; j++) {
            float v = 0.f;
#pragma unroll
            for (int k = 0; k < 10; k++) v += x[k] * sW1[k * 10 + j];
            yn[j] = v;
        }
        unsigned r0 = (unsigned)f2bf(yn[0]) | ((unsigned)f2bf(yn[1]) << 16);
        unsigned r1 = (unsigned)f2bf(yn[2]) | ((unsigned)f2bf(yn[3]) << 16);
        unsigned r2 = (unsigned)f2bf(yn[4]) | ((unsigned)f2bf(yn[5]) << 16);
        unsigned r3 = (unsigned)f2bf(yn[6]) | ((unsigned)f2bf(yn[7]) << 16);
        unsigned r4 = (unsigned)f2bf(yn[8]) | ((unsigned)f2bf(yn[9]) << 16);
        unsigned* yo = yout + (size_t)n * 8;
        *(uint4*)yo = make_uint4(r0, r1, r2, r3);
        yo[4] = r4;
    }
}

// ---------------- Final: out[g] = sigmoid(gacc[g] / max(count,1)) ----------------
__global__ void k4_final(const float* __restrict__ gacc, const int* __restrict__ node_graph,
                         float* __restrict__ out, int N, int G) {
    int g = blockIdx.x * blockDim.x + threadIdx.x;
    if (g >= G) return;
    int lo = 0, hi = N;
    while (lo < hi) { int m = (lo + hi) >> 1; if (node_graph[m] < g) lo = m + 1; else hi = m; }
    int lo2 = lo, hi2 = N;
    while (lo2 < hi2) { int m = (lo2 + hi2) >> 1; if (node_graph[m] <= g) lo2 = m + 1; else hi2 = m; }
    float c = (float)(hi2 - lo);
    if (c < 1.f) c = 1.f;
    float s = gacc[g] / c;
    out[g] = 1.f / (1.f + __expf(-s));
}

// ============ R4 fallback fused layer (f32 rows, src-only edges) ============
__global__ __launch_bounds__(256) void k_layer(
        const float* __restrict__ yin, float* __restrict__ yout,
        const unsigned* __restrict__ row_start, const unsigned* __restrict__ edges,
        const float* __restrict__ b1, const float* __restrict__ W2,
        const float* __restrict__ b2, const float* __restrict__ l,
        const float* __restrict__ W1n,
        const int* __restrict__ node_graph, float* __restrict__ gacc,
        int N, int last) {
    __shared__ float sW2[100], sW1[100], sb1[10], sb2[10], sl[10];
    int t = threadIdx.x;
    if (t < 100) sW2[t] = W2[t];
    if (!last && t >= 128 && t < 228) sW1[t - 128] = W1n[t - 128];
    if (t < 10) { sb1[t] = b1[t]; sb2[t] = b2[t]; sl[t] = l[t]; }
    __syncthreads();
    int n = blockIdx.x * 256 + t;
    bool valid = n < N;
    int nc = valid ? n : (N - 1);
    const float* yr = yin + (size_t)nc * 16;
    float4 a = *(const float4*)yr;
    float4 b = *(const float4*)(yr + 4);
    float2 c = *(const float2*)(yr + 8);
    float acc[10] = {a.x, a.y, a.z, a.w, b.x, b.y, b.z, b.w, c.x, c.y};
    unsigned beg = 0, end = 0;
    if (valid) { beg = row_start[n]; end = row_start[n + 1]; }
    for (unsigned e = beg; e < end; ++e) {
        unsigned s = edges[e];
        const float* pr = yin + (size_t)s * 16;
        float4 pa = *(const float4*)pr;
        float4 pb = *(const float4*)(pr + 4);
        float2 pc = *(const float2*)(pr + 8);
        acc[0] += pa.x; acc[1] += pa.y; acc[2] += pa.z; acc[3] += pa.w;
        acc[4] += pb.x; acc[5] += pb.y; acc[6] += pb.z; acc[7] += pb.w;
        acc[8] += pc.x; acc[9] += pc.y;
    }
    float z[10], x[10];
#pragma unroll
    for (int j = 0; j < 10; j++) {
        float v = acc[j] + sb1[j];
        z[j] = v > 0.f ? v : 0.f;
    }
#pragma unroll
    for (int j = 0; j < 10; j++) {
        float v = sb2[j];
#pragma unroll
        for (int k = 0; k < 10; k++) v += z[k] * sW2[k * 10 + j];
        x[j] = v > 0.f ? v : 0.f;
    }
    float p = 0.f;
#pragma unroll
    for (int j = 0; j < 10; j++) p += x[j] * sl[j];
    if (!valid) p = 0.f;
    int g = node_graph[nc];
    int g0 = __shfl(g, 0);
    if (__all(g == g0)) {
#pragma unroll
        for (int off = 32; off > 0; off >>= 1) p += __shfl_down(p, off);
        if ((t & 63) == 0) unsafeAtomicAdd(&gacc[g0], p);
    } else {
        if (valid) unsafeAtomicAdd(&gacc[g], p);
    }
    if (!last && valid) {
        float yn[10];
#pragma unroll
        for (int j = 0; j < 10; j++) {
            float v = 0.f;
#pragma unroll
            for (int k = 0; k < 10; k++) v += x[k] * sW1[k * 10 + j];
            yn[j] = v;
        }
        float* yo = yout + (size_t)n * 16;
        *(float4*)yo = make_float4(yn[0], yn[1], yn[2], yn[3]);
        *(float4*)(yo + 4) = make_float4(yn[4], yn[5], yn[6], yn[7]);
        *(float2*)(yo + 8) = make_float2(yn[8], yn[9]);
    }
}

static inline size_t al16(size_t w) { return (w + 15) & ~(size_t)15; }

extern "C" void kernel_launch(void* const* d_in, const int* in_sizes, int n_in,
                              void* d_out, int out_size, void* d_ws, size_t ws_size,
                              hipStream_t stream) {
    const float* h  = (const float*)d_in[0];
    const int* src  = (const int*)d_in[1];
    const int* dst  = (const int*)d_in[2];
    const int* ng   = (const int*)d_in[3];
    int N = in_sizes[3];
    int E = in_sizes[1];
    int G = out_size;

    const float* W1[5]; const float* b1[5]; const float* W2[5]; const float* b2[5]; const float* l[5];
    for (int i = 0; i < 5; i++) {
        W1[i] = (const float*)d_in[4 + i * 5 + 0];
        b1[i] = (const float*)d_in[4 + i * 5 + 1];
        W2[i] = (const float*)d_in[4 + i * 5 + 2];
        b2[i] = (const float*)d_in[4 + i * 5 + 3];
        l[i]  = (const float*)d_in[4 + i * 5 + 4];
    }
    float* out = (float*)d_out;

    int B = (N + 1023) >> 10;
    int W = (E + 63) >> 6;

    // R6 layout (4B words, each region 16-word aligned):
    //   y0[N*8 bf16] | reg2 = max(pairs[E], y1[N*8]) | edges[E] | row_start[N+1]
    //   | agg[N*16 f32] | carry_val[W*16] | carry_dst[W] | buckets(512+513+512) | gacc[G]
    size_t wY   = al16((size_t)N * 8);
    size_t wRg2 = al16(((size_t)E > (size_t)N * 8) ? (size_t)E : (size_t)N * 8);
    size_t wE   = al16((size_t)E);
    size_t wRS  = al16((size_t)N + 1);
    size_t wAgg = al16((size_t)N * 16);
    size_t wCV  = al16((size_t)W * 16);
    size_t wCD  = al16((size_t)W);
    size_t need_r6 = (wY + wRg2 + wE + wRS + wAgg + wCV + wCD + 1552 + al16((size_t)G)) * 4;

    size_t regAB = (size_t)N * 16;
    size_t reg2f = ((size_t)E > regAB) ? (size_t)E : regAB;
    size_t need_r4 = (regAB + reg2f + (size_t)E + (size_t)(N + 1) + 1537 + (size_t)G) * 4;

    if (ws_size >= need_r6 && B <= 512) {
        unsigned* y0 = (unsigned*)d_ws;
        unsigned* pairs = y0 + wY;
        unsigned* y1 = pairs;              // pairs dead after k_p2
        unsigned* edges = pairs + wRg2;
        unsigned* row_start = edges + wE;
        float* agg = (float*)(row_start + wRS);
        float* carry_val = agg + wAgg;
        unsigned* carry_dst = (unsigned*)(carry_val + wCV);
        unsigned* bucket_cnt = carry_dst + wCD;
        unsigned* bbase = bucket_cnt + 512;
        unsigned* bcur = bbase + 513;
        float* gacc = (float*)(bcur + 512);

        hipMemsetAsync(bucket_cnt, 0, 512 * 4, stream);
        hipMemsetAsync(gacc, 0, (size_t)G * 4, stream);

        k1_hw1_bf16<<<(N + 255) / 256, 256, 0, stream>>>(h, W1[0], y0, N);

        k_bhist<<<2048, 256, 0, stream>>>(dst, bucket_cnt, E);
        k_bscan<<<1, 512, 0, stream>>>(bucket_cnt, bbase, bcur, B);
        k_bscatter2<<<256, 1024, 0, stream>>>(src, dst, bcur, pairs, E, 256);
        k_p2<<<B, 1024, 0, stream>>>(pairs, bbase, edges, row_start, N, B, E, 1);

        unsigned* ybuf[2] = {y0, y1};
        int ablocks = (W + 3) / 4;
        for (int i = 0; i < 5; i++) {
            kA_agg<<<ablocks, 256, 0, stream>>>(
                ybuf[i & 1], edges, bbase, agg, carry_val, carry_dst, E, B, W);
            kB_node<<<(N + 255) / 256, 256, 0, stream>>>(
                ybuf[i & 1], ybuf[(i + 1) & 1], agg, row_start, carry_dst, carry_val,
                b1[i], W2[i], b2[i], l[i], i < 4 ? W1[i + 1] : nullptr,
                ng, gacc, N, i == 4 ? 1 : 0);
        }
        k4_final<<<(G + 255) / 256, 256, 0, stream>>>(gacc, ng, out, N, G);
        return;
    }

    // fallback: R4 path (f32 rows, fused node-parallel layer)
    if (ws_size >= need_r4 && B <= 512) {
        float* y0 = (float*)d_ws;
        unsigned* pairs = (unsigned*)(y0 + regAB);
        float* y1 = (float*)pairs;
        unsigned* edges = pairs + reg2f;
        unsigned* row_start = edges + E;
        unsigned* bucket_cnt = row_start + (N + 1);
        unsigned* bbase = bucket_cnt + 512;
        unsigned* bcur = bbase + 513;
        float* gacc = (float*)(bcur + 512);

        hipMemsetAsync(bucket_cnt, 0, 512 * 4, stream);
        hipMemsetAsync(gacc, 0, (size_t)G * 4, stream);

        k1_hw1_f32<<<(N + 255) / 256, 256, 0, stream>>>(h, W1[0], y0, N);
        k_bhist<<<2048, 256, 0, stream>>>(dst, bucket_cnt, E);
        k_bscan<<<1, 512, 0, stream>>>(bucket_cnt, bbase, bcur, B);
        k_bscatter2<<<256, 1024, 0, stream>>>(src, dst, bcur, pairs, E, 256);
        k_p2<<<B, 1024, 0, stream>>>(pairs, bbase, edges, row_start, N, B, E, 0);

        float* ybuf[2] = {y0, y1};
        for (int i = 0; i < 5; i++) {
            k_layer<<<(N + 255) / 256, 256, 0, stream>>>(
                ybuf[i & 1], ybuf[(i + 1) & 1], row_start, edges,
                b1[i], W2[i], b2[i], l[i], i < 4 ? W1[i + 1] : nullptr,
                ng, gacc, N, i == 4 ? 1 : 0);
        }
        k4_final<<<(G + 255) / 256, 256, 0, stream>>>(gacc, ng, out, N, G);
    }
}

// Round 7
// 2300.056 us; speedup vs baseline: 3.2938x; 1.0208x over previous
//
#include <hip/hip_runtime.h>

// GIN: 5 layers, DIM=10. Identity: (x+agg)@W1 = x@W1 + segsum((x@W1)[src]).
// R7: kA processes 2 edges/lane (128-edge waves) -> segmented-scan cost per
// edge halved (R6 showed kA VALU-bound at 59% VALUBusy). bf16 y rows (32B),
// bucketed CSR build with block-aggregated reservation, zero hot-phase atomics.

#define SENTINEL 0xFFFFFFFFu

__device__ __forceinline__ unsigned short f2bf(float f) {
    unsigned b = __float_as_uint(f);
    b += 0x7fffu + ((b >> 16) & 1u);   // round-to-nearest-even
    return (unsigned short)(b >> 16);
}
__device__ __forceinline__ float bflo(unsigned u) { return __uint_as_float(u << 16); }
__device__ __forceinline__ float bfhi(unsigned u) { return __uint_as_float(u & 0xffff0000u); }

// ---------------- Layer-1: y = h @ W1_1 (bf16 rows, 8 uints/row) ----------------
__global__ void k1_hw1_bf16(const float* __restrict__ h, const float* __restrict__ W1,
                            unsigned* __restrict__ y, int N) {
    __shared__ float sW[640];
    for (int i = threadIdx.x; i < 640; i += blockDim.x) sW[i] = W1[i];
    __syncthreads();
    int n = blockIdx.x * blockDim.x + threadIdx.x;
    if (n >= N) return;
    const float* hr = h + (size_t)n * 64;
    float acc[10];
#pragma unroll
    for (int j = 0; j < 10; j++) acc[j] = 0.f;
#pragma unroll 4
    for (int k = 0; k < 64; k += 4) {
        float4 hv = *(const float4*)(hr + k);
#pragma unroll
        for (int j = 0; j < 10; j++) {
            acc[j] += hv.x * sW[(k + 0) * 10 + j];
            acc[j] += hv.y * sW[(k + 1) * 10 + j];
            acc[j] += hv.z * sW[(k + 2) * 10 + j];
            acc[j] += hv.w * sW[(k + 3) * 10 + j];
        }
    }
    unsigned r0 = (unsigned)f2bf(acc[0]) | ((unsigned)f2bf(acc[1]) << 16);
    unsigned r1 = (unsigned)f2bf(acc[2]) | ((unsigned)f2bf(acc[3]) << 16);
    unsigned r2 = (unsigned)f2bf(acc[4]) | ((unsigned)f2bf(acc[5]) << 16);
    unsigned r3 = (unsigned)f2bf(acc[6]) | ((unsigned)f2bf(acc[7]) << 16);
    unsigned r4 = (unsigned)f2bf(acc[8]) | ((unsigned)f2bf(acc[9]) << 16);
    unsigned* yr = y + (size_t)n * 8;
    *(uint4*)yr = make_uint4(r0, r1, r2, r3);
    yr[4] = r4;
}

// f32 variant for the fallback path (16-float rows)
__global__ void k1_hw1_f32(const float* __restrict__ h, const float* __restrict__ W1,
                           float* __restrict__ y, int N) {
    __shared__ float sW[640];
    for (int i = threadIdx.x; i < 640; i += blockDim.x) sW[i] = W1[i];
    __syncthreads();
    int n = blockIdx.x * blockDim.x + threadIdx.x;
    if (n >= N) return;
    const float* hr = h + (size_t)n * 64;
    float acc[10];
#pragma unroll
    for (int j = 0; j < 10; j++) acc[j] = 0.f;
#pragma unroll 4
    for (int k = 0; k < 64; k += 4) {
        float4 hv = *(const float4*)(hr + k);
#pragma unroll
        for (int j = 0; j < 10; j++) {
            acc[j] += hv.x * sW[(k + 0) * 10 + j];
            acc[j] += hv.y * sW[(k + 1) * 10 + j];
            acc[j] += hv.z * sW[(k + 2) * 10 + j];
            acc[j] += hv.w * sW[(k + 3) * 10 + j];
        }
    }
    float* yr = y + (size_t)n * 16;
#pragma unroll
    for (int j = 0; j < 10; j++) yr[j] = acc[j];
}

// =================== CSR build: two-level bucket split ===================
__global__ void k_bhist(const int* __restrict__ dst, unsigned* __restrict__ bucket_cnt,
                        int E) {
    __shared__ unsigned h[512];
    int t = threadIdx.x;
    h[t] = 0; h[t + 256] = 0;
    __syncthreads();
    int stride = gridDim.x * blockDim.x;
    for (int e = blockIdx.x * blockDim.x + t; e < E; e += stride)
        atomicAdd(&h[(unsigned)dst[e] >> 10], 1u);
    __syncthreads();
    if (h[t]) atomicAdd(&bucket_cnt[t], h[t]);
    if (h[t + 256]) atomicAdd(&bucket_cnt[t + 256], h[t + 256]);
}

__global__ void k_bscan(const unsigned* __restrict__ bucket_cnt,
                        unsigned* __restrict__ bbase, unsigned* __restrict__ bcur, int B) {
    __shared__ unsigned s[512];
    int t = threadIdx.x;
    unsigned v = (t < B) ? bucket_cnt[t] : 0u;
    s[t] = v;
    __syncthreads();
    for (int off = 1; off < 512; off <<= 1) {
        unsigned u = (t >= off) ? s[t - off] : 0u;
        __syncthreads();
        s[t] += u;
        __syncthreads();
    }
    unsigned excl = s[t] - v;
    if (t < B) { bbase[t] = excl; bcur[t] = excl; }
    if (t == B - 1) bbase[B] = s[t];
}

__global__ __launch_bounds__(1024) void k_bscatter2(
        const int* __restrict__ src, const int* __restrict__ dst,
        unsigned* __restrict__ bcur, unsigned* __restrict__ pairs,
        int E, int nblocks) {
    __shared__ unsigned cnt[512];
    int t = threadIdx.x;
    int per = (E + nblocks - 1) / nblocks;
    int beg = blockIdx.x * per;
    int end = beg + per; if (end > E) end = E;
    if (beg >= E) return;
    if (t < 512) cnt[t] = 0;
    __syncthreads();
    for (int e = beg + t; e < end; e += 1024)
        atomicAdd(&cnt[(unsigned)dst[e] >> 10], 1u);
    __syncthreads();
    unsigned c = 0, base = 0;
    if (t < 512) { c = cnt[t]; if (c) base = atomicAdd(&bcur[t], c); }
    __syncthreads();
    if (t < 512) cnt[t] = base;
    __syncthreads();
    for (int e = beg + t; e < end; e += 1024) {
        unsigned d = (unsigned)dst[e];
        unsigned pos = atomicAdd(&cnt[d >> 10], 1u);
        pairs[pos] = ((unsigned)src[e] << 10) | (d & 1023u);
    }
}

__global__ __launch_bounds__(1024) void k_p2(
        const unsigned* __restrict__ pairs, const unsigned* __restrict__ bbase,
        unsigned* __restrict__ edges, unsigned* __restrict__ row_start,
        int N, int B, int E, int packed) {
    __shared__ unsigned cnt[1024], scn[1024], cur[1024];
    int t = threadIdx.x, b = blockIdx.x;
    unsigned beg = bbase[b], end = bbase[b + 1];
    cnt[t] = 0;
    __syncthreads();
    for (unsigned e = beg + t; e < end; e += 1024)
        atomicAdd(&cnt[pairs[e] & 1023u], 1u);
    __syncthreads();
    unsigned v = cnt[t];
    scn[t] = v;
    __syncthreads();
    for (int off = 1; off < 1024; off <<= 1) {
        unsigned u = (t >= off) ? scn[t - off] : 0u;
        __syncthreads();
        scn[t] += u;
        __syncthreads();
    }
    unsigned excl = scn[t] - v;
    int node = (b << 10) + t;
    if (node < N) row_start[node] = beg + excl;
    if (b == B - 1 && t == 0) row_start[N] = (unsigned)E;
    cur[t] = beg + excl;
    __syncthreads();
    for (unsigned e = beg + t; e < end; e += 1024) {
        unsigned pv = pairs[e];
        unsigned pos = atomicAdd(&cur[pv & 1023u], 1u);
        edges[pos] = packed ? pv : (pv >> 10);
    }
}

// =================== hot phase ===================
// kA: TWO edges per lane (wave spans 128 edges). Pair-combine locally; rare
// internal-boundary segments (~3% of lanes) handled on a wave-uniform slow
// path. Segmented scan runs once per 128 edges.
__global__ __launch_bounds__(256) void kA_agg(
        const unsigned* __restrict__ yin, const unsigned* __restrict__ epk,
        const unsigned* __restrict__ bbase,
        float* __restrict__ agg, float* __restrict__ carry_val,
        unsigned* __restrict__ carry_dst, int E, int B, int W2) {
    __shared__ unsigned sb[513];
    for (int i = threadIdx.x; i < B + 1; i += 256) sb[i] = bbase[i];
    __syncthreads();
    int lane = threadIdx.x & 63;
    int w = blockIdx.x * 4 + (threadIdx.x >> 6);
    int e0 = (w << 7) + (lane << 1);
    int e1 = e0 + 1;
    bool v0 = e0 < E, v1 = e1 < E;

    unsigned dst0 = SENTINEL, sdst = SENTINEL, first_dst = SENTINEL;
    bool internal = false;
    float a0[10], sacc[10];
#pragma unroll
    for (int j = 0; j < 10; j++) { a0[j] = 0.f; sacc[j] = 0.f; }

    if (v0) {
        unsigned pv0, pv1 = 0;
        if (v1) { uint2 pp = *(const uint2*)(epk + e0); pv0 = pp.x; pv1 = pp.y; }
        else pv0 = epk[e0];
        int lo = 0, hi = B - 1;
        while (lo < hi) { int m = (lo + hi + 1) >> 1; if (sb[m] <= (unsigned)e0) lo = m; else hi = m - 1; }
        dst0 = ((unsigned)lo << 10) | (pv0 & 1023u);
        first_dst = dst0;
        const unsigned* p0 = yin + (size_t)(pv0 >> 10) * 8;
        uint4 q0 = *(const uint4*)p0;
        unsigned q04 = p0[4];
        float r0[10] = {bflo(q0.x), bfhi(q0.x), bflo(q0.y), bfhi(q0.y),
                        bflo(q0.z), bfhi(q0.z), bflo(q0.w), bfhi(q0.w),
                        bflo(q04),  bfhi(q04)};
        if (v1) {
            int b1 = lo;
            while (b1 < B - 1 && sb[b1 + 1] <= (unsigned)e1) b1++;
            unsigned dst1 = ((unsigned)b1 << 10) | (pv1 & 1023u);
            const unsigned* p1 = yin + (size_t)(pv1 >> 10) * 8;
            uint4 q1 = *(const uint4*)p1;
            unsigned q14 = p1[4];
            float r1[10] = {bflo(q1.x), bfhi(q1.x), bflo(q1.y), bfhi(q1.y),
                            bflo(q1.z), bfhi(q1.z), bflo(q1.w), bfhi(q1.w),
                            bflo(q14),  bfhi(q14)};
            if (dst1 == dst0) {
                sdst = dst0;
#pragma unroll
                for (int j = 0; j < 10; j++) sacc[j] = r0[j] + r1[j];
            } else {
                internal = true;
                sdst = dst1;
#pragma unroll
                for (int j = 0; j < 10; j++) { a0[j] = r0[j]; sacc[j] = r1[j]; }
            }
        } else {
            sdst = dst0;
#pragma unroll
            for (int j = 0; j < 10; j++) sacc[j] = r0[j];
        }
    }

    // segmented inclusive scan over (sdst, sacc)
#pragma unroll
    for (int off = 1; off < 64; off <<= 1) {
        unsigned od = __shfl_up(sdst, off);
        float tv[10];
#pragma unroll
        for (int j = 0; j < 10; j++) tv[j] = __shfl_up(sacc[j], off);
        bool take = (lane >= off) && (od == sdst);
#pragma unroll
        for (int j = 0; j < 10; j++) sacc[j] = take ? sacc[j] + tv[j] : sacc[j];
    }

    // rare path: internal-boundary segments (dst0 run ends at this lane's 1st slot)
    if (__any(internal)) {
        unsigned pdst = __shfl_up(sdst, 1);
        float pacc[10];
#pragma unroll
        for (int j = 0; j < 10; j++) pacc[j] = __shfl_up(sacc[j], 1);
        if (internal) {
            bool ci = (lane > 0) && (pdst == dst0);
            float* ar = agg + (size_t)dst0 * 16;
            float t0 = a0[0] + (ci ? pacc[0] : 0.f);
            float t1 = a0[1] + (ci ? pacc[1] : 0.f);
            float t2 = a0[2] + (ci ? pacc[2] : 0.f);
            float t3 = a0[3] + (ci ? pacc[3] : 0.f);
            float t4 = a0[4] + (ci ? pacc[4] : 0.f);
            float t5 = a0[5] + (ci ? pacc[5] : 0.f);
            float t6 = a0[6] + (ci ? pacc[6] : 0.f);
            float t7 = a0[7] + (ci ? pacc[7] : 0.f);
            float t8 = a0[8] + (ci ? pacc[8] : 0.f);
            float t9 = a0[9] + (ci ? pacc[9] : 0.f);
            *(float4*)ar = make_float4(t0, t1, t2, t3);
            *(float4*)(ar + 4) = make_float4(t4, t5, t6, t7);
            *(float2*)(ar + 8) = make_float2(t8, t9);
        }
    }

    unsigned nfirst = __shfl_down(first_dst, 1);
    bool is_end = (lane < 63) && (sdst != nfirst);
    if (v0 && is_end) {
        float* ar = agg + (size_t)sdst * 16;
        *(float4*)ar = make_float4(sacc[0], sacc[1], sacc[2], sacc[3]);
        *(float4*)(ar + 4) = make_float4(sacc[4], sacc[5], sacc[6], sacc[7]);
        *(float2*)(ar + 8) = make_float2(sacc[8], sacc[9]);
    }
    if (lane == 63 && w < W2) {
        carry_dst[w] = sdst;
        float* cr = carry_val + (size_t)w * 16;
        *(float4*)cr = make_float4(sacc[0], sacc[1], sacc[2], sacc[3]);
        *(float4*)(cr + 4) = make_float4(sacc[4], sacc[5], sacc[6], sacc[7]);
        *(float2*)(cr + 8) = make_float2(sacc[8], sacc[9]);
    }
}

// kB: node-parallel MLP; reconstructs agg from interior store + wave carries.
// 128-edge waves: carry-only iff (le&127)==127 or (le==E-1 && (le&127)==126).
__global__ __launch_bounds__(256) void kB_node(
        const unsigned* __restrict__ yin, unsigned* __restrict__ yout,
        const float* __restrict__ agg,
        const unsigned* __restrict__ row_start,
        const unsigned* __restrict__ carry_dst, const float* __restrict__ carry_val,
        const float* __restrict__ b1, const float* __restrict__ W2,
        const float* __restrict__ b2, const float* __restrict__ l,
        const float* __restrict__ W1n,
        const int* __restrict__ node_graph, float* __restrict__ gacc,
        int N, int E, int last) {
    __shared__ float sW2[100], sW1[100], sb1[10], sb2[10], sl[10];
    int t = threadIdx.x;
    if (t < 100) sW2[t] = W2[t];
    if (!last && t >= 128 && t < 228) sW1[t - 128] = W1n[t - 128];
    if (t < 10) { sb1[t] = b1[t]; sb2[t] = b2[t]; sl[t] = l[t]; }
    __syncthreads();
    int n = blockIdx.x * 256 + t;
    bool valid = n < N;
    int nc = valid ? n : (N - 1);
    const unsigned* yr = yin + (size_t)nc * 8;
    uint4 q = *(const uint4*)yr;
    unsigned q4 = yr[4];
    float acc[10] = {bflo(q.x), bfhi(q.x), bflo(q.y), bfhi(q.y),
                     bflo(q.z), bfhi(q.z), bflo(q.w), bfhi(q.w),
                     bflo(q4),  bfhi(q4)};

    if (valid) {
        unsigned rs0 = row_start[n], rs1 = row_start[n + 1];
        if (rs1 > rs0) {
            unsigned le = rs1 - 1;
            bool carry_only = ((le & 127u) == 127u) ||
                              ((le == (unsigned)(E - 1)) && ((le & 127u) == 126u));
            if (!carry_only) {
                const float* ar = agg + (size_t)n * 16;
                float4 pa = *(const float4*)ar;
                float4 pb = *(const float4*)(ar + 4);
                float2 pc = *(const float2*)(ar + 8);
                acc[0] += pa.x; acc[1] += pa.y; acc[2] += pa.z; acc[3] += pa.w;
                acc[4] += pb.x; acc[5] += pb.y; acc[6] += pb.z; acc[7] += pb.w;
                acc[8] += pc.x; acc[9] += pc.y;
            }
            unsigned w0 = rs0 >> 7, w1 = le >> 7;
            for (unsigned w = w0; w <= w1; ++w) {
                if (carry_dst[w] == (unsigned)n) {
                    const float* cr = carry_val + (size_t)w * 16;
                    float4 pa = *(const float4*)cr;
                    float4 pb = *(const float4*)(cr + 4);
                    float2 pc = *(const float2*)(cr + 8);
                    acc[0] += pa.x; acc[1] += pa.y; acc[2] += pa.z; acc[3] += pa.w;
                    acc[4] += pb.x; acc[5] += pb.y; acc[6] += pb.z; acc[7] += pb.w;
                    acc[8] += pc.x; acc[9] += pc.y;
                }
            }
        }
    }

    float z[10], x[10];
#pragma unroll
    for (int j = 0; j < 10; j++) {
        float v = acc[j] + sb1[j];
        z[j] = v > 0.f ? v : 0.f;
    }
#pragma unroll
    for (int j = 0; j < 10; j++) {
        float v = sb2[j];
#pragma unroll
        for (int k = 0; k < 10; k++) v += z[k] * sW2[k * 10 + j];
        x[j] = v > 0.f ? v : 0.f;
    }
    float p = 0.f;
#pragma unroll
    for (int j = 0; j < 10; j++) p += x[j] * sl[j];
    if (!valid) p = 0.f;
    int g = node_graph[nc];

    int g0 = __shfl(g, 0);
    if (__all(g == g0)) {
#pragma unroll
        for (int off = 32; off > 0; off >>= 1) p += __shfl_down(p, off);
        if ((t & 63) == 0) unsafeAtomicAdd(&gacc[g0], p);
    } else {
        if (valid) unsafeAtomicAdd(&gacc[g], p);
    }

    if (!last && valid) {
        float yn[10];
#pragma unroll
        for (int j = 0; j < 10; j++) {
            float v = 0.f;
#pragma unroll
            for (int k = 0; k < 10; k++) v += x[k] * sW1[k * 10 + j];
            yn[j] = v;
        }
        unsigned r0 = (unsigned)f2bf(yn[0]) | ((unsigned)f2bf(yn[1]) << 16);
        unsigned r1 = (unsigned)f2bf(yn[2]) | ((unsigned)f2bf(yn[3]) << 16);
        unsigned r2 = (unsigned)f2bf(yn[4]) | ((unsigned)f2bf(yn[5]) << 16);
        unsigned r3 = (unsigned)f2bf(yn[6]) | ((unsigned)f2bf(yn[7]) << 16);
        unsigned r4 = (unsigned)f2bf(yn[8]) | ((unsigned)f2bf(yn[9]) << 16);
        unsigned* yo = yout + (size_t)n * 8;
        *(uint4*)yo = make_uint4(r0, r1, r2, r3);
        yo[4] = r4;
    }
}

// ---------------- Final: out[g] = sigmoid(gacc[g] / max(count,1)) ----------------
__global__ void k4_final(const float* __restrict__ gacc, const int* __restrict__ node_graph,
                         float* __restrict__ out, int N, int G) {
    int g = blockIdx.x * blockDim.x + threadIdx.x;
    if (g >= G) return;
    int lo = 0, hi = N;
    while (lo < hi) { int m = (lo + hi) >> 1; if (node_graph[m] < g) lo = m + 1; else hi = m; }
    int lo2 = lo, hi2 = N;
    while (lo2 < hi2) { int m = (lo2 + hi2) >> 1; if (node_graph[m] <= g) lo2 = m + 1; else hi2 = m; }
    float c = (float)(hi2 - lo);
    if (c < 1.f) c = 1.f;
    float s = gacc[g] / c;
    out[g] = 1.f / (1.f + __expf(-s));
}

// ============ R4 fallback fused layer (f32 rows, src-only edges) ============
__global__ __launch_bounds__(256) void k_layer(
        const float* __restrict__ yin, float* __restrict__ yout,
        const unsigned* __restrict__ row_start, const unsigned* __restrict__ edges,
        const float* __restrict__ b1, const float* __restrict__ W2,
        const float* __restrict__ b2, const float* __restrict__ l,
        const float* __restrict__ W1n,
        const int* __restrict__ node_graph, float* __restrict__ gacc,
        int N, int last) {
    __shared__ float sW2[100], sW1[100], sb1[10], sb2[10], sl[10];
    int t = threadIdx.x;
    if (t < 100) sW2[t] = W2[t];
    if (!last && t >= 128 && t < 228) sW1[t - 128] = W1n[t - 128];
    if (t < 10) { sb1[t] = b1[t]; sb2[t] = b2[t]; sl[t] = l[t]; }
    __syncthreads();
    int n = blockIdx.x * 256 + t;
    bool valid = n < N;
    int nc = valid ? n : (N - 1);
    const float* yr = yin + (size_t)nc * 16;
    float4 a = *(const float4*)yr;
    float4 b = *(const float4*)(yr + 4);
    float2 c = *(const float2*)(yr + 8);
    float acc[10] = {a.x, a.y, a.z, a.w, b.x, b.y, b.z, b.w, c.x, c.y};
    unsigned beg = 0, end = 0;
    if (valid) { beg = row_start[n]; end = row_start[n + 1]; }
    for (unsigned e = beg; e < end; ++e) {
        unsigned s = edges[e];
        const float* pr = yin + (size_t)s * 16;
        float4 pa = *(const float4*)pr;
        float4 pb = *(const float4*)(pr + 4);
        float2 pc = *(const float2*)(pr + 8);
        acc[0] += pa.x; acc[1] += pa.y; acc[2] += pa.z; acc[3] += pa.w;
        acc[4] += pb.x; acc[5] += pb.y; acc[6] += pb.z; acc[7] += pb.w;
        acc[8] += pc.x; acc[9] += pc.y;
    }
    float z[10], x[10];
#pragma unroll
    for (int j = 0; j < 10; j++) {
        float v = acc[j] + sb1[j];
        z[j] = v > 0.f ? v : 0.f;
    }
#pragma unroll
    for (int j = 0; j < 10; j++) {
        float v = sb2[j];
#pragma unroll
        for (int k = 0; k < 10; k++) v += z[k] * sW2[k * 10 + j];
        x[j] = v > 0.f ? v : 0.f;
    }
    float p = 0.f;
#pragma unroll
    for (int j = 0; j < 10; j++) p += x[j] * sl[j];
    if (!valid) p = 0.f;
    int g = node_graph[nc];
    int g0 = __shfl(g, 0);
    if (__all(g == g0)) {
#pragma unroll
        for (int off = 32; off > 0; off >>= 1) p += __shfl_down(p, off);
        if ((t & 63) == 0) unsafeAtomicAdd(&gacc[g0], p);
    } else {
        if (valid) unsafeAtomicAdd(&gacc[g], p);
    }
    if (!last && valid) {
        float yn[10];
#pragma unroll
        for (int j = 0; j < 10; j++) {
            float v = 0.f;
#pragma unroll
            for (int k = 0; k < 10; k++) v += x[k] * sW1[k * 10 + j];
            yn[j] = v;
        }
        float* yo = yout + (size_t)n * 16;
        *(float4*)yo = make_float4(yn[0], yn[1], yn[2], yn[3]);
        *(float4*)(yo + 4) = make_float4(yn[4], yn[5], yn[6], yn[7]);
        *(float2*)(yo + 8) = make_float2(yn[8], yn[9]);
    }
}

static inline size_t al16(size_t w) { return (w + 15) & ~(size_t)15; }

extern "C" void kernel_launch(void* const* d_in, const int* in_sizes, int n_in,
                              void* d_out, int out_size, void* d_ws, size_t ws_size,
                              hipStream_t stream) {
    const float* h  = (const float*)d_in[0];
    const int* src  = (const int*)d_in[1];
    const int* dst  = (const int*)d_in[2];
    const int* ng   = (const int*)d_in[3];
    int N = in_sizes[3];
    int E = in_sizes[1];
    int G = out_size;

    const float* W1[5]; const float* b1[5]; const float* W2[5]; const float* b2[5]; const float* l[5];
    for (int i = 0; i < 5; i++) {
        W1[i] = (const float*)d_in[4 + i * 5 + 0];
        b1[i] = (const float*)d_in[4 + i * 5 + 1];
        W2[i] = (const float*)d_in[4 + i * 5 + 2];
        b2[i] = (const float*)d_in[4 + i * 5 + 3];
        l[i]  = (const float*)d_in[4 + i * 5 + 4];
    }
    float* out = (float*)d_out;

    int B = (N + 1023) >> 10;
    int W2n = (E + 127) >> 7;   // 128-edge waves

    // R7 layout (4B words, 16-word aligned regions):
    //   y0[N*8] | reg2=max(pairs[E], y1[N*8]) | edges[E] | row_start[N+1]
    //   | agg[N*16] | carry_val[W2*16] | carry_dst[W2] | buckets | gacc[G]
    size_t wY   = al16((size_t)N * 8);
    size_t wRg2 = al16(((size_t)E > (size_t)N * 8) ? (size_t)E : (size_t)N * 8);
    size_t wE   = al16((size_t)E);
    size_t wRS  = al16((size_t)N + 1);
    size_t wAgg = al16((size_t)N * 16);
    size_t wCV  = al16((size_t)W2n * 16);
    size_t wCD  = al16((size_t)W2n);
    size_t need_r7 = (wY + wRg2 + wE + wRS + wAgg + wCV + wCD + 1552 + al16((size_t)G)) * 4;

    size_t regAB = (size_t)N * 16;
    size_t reg2f = ((size_t)E > regAB) ? (size_t)E : regAB;
    size_t need_r4 = (regAB + reg2f + (size_t)E + (size_t)(N + 1) + 1537 + (size_t)G) * 4;

    if (ws_size >= need_r7 && B <= 512) {
        unsigned* y0 = (unsigned*)d_ws;
        unsigned* pairs = y0 + wY;
        unsigned* y1 = pairs;              // pairs dead after k_p2
        unsigned* edges = pairs + wRg2;
        unsigned* row_start = edges + wE;
        float* agg = (float*)(row_start + wRS);
        float* carry_val = agg + wAgg;
        unsigned* carry_dst = (unsigned*)(carry_val + wCV);
        unsigned* bucket_cnt = carry_dst + wCD;
        unsigned* bbase = bucket_cnt + 512;
        unsigned* bcur = bbase + 513;
        float* gacc = (float*)(bcur + 512);

        hipMemsetAsync(bucket_cnt, 0, 512 * 4, stream);
        hipMemsetAsync(gacc, 0, (size_t)G * 4, stream);

        k1_hw1_bf16<<<(N + 255) / 256, 256, 0, stream>>>(h, W1[0], y0, N);

        k_bhist<<<2048, 256, 0, stream>>>(dst, bucket_cnt, E);
        k_bscan<<<1, 512, 0, stream>>>(bucket_cnt, bbase, bcur, B);
        k_bscatter2<<<256, 1024, 0, stream>>>(src, dst, bcur, pairs, E, 256);
        k_p2<<<B, 1024, 0, stream>>>(pairs, bbase, edges, row_start, N, B, E, 1);

        unsigned* ybuf[2] = {y0, y1};
        int ablocks = (W2n + 3) / 4;
        for (int i = 0; i < 5; i++) {
            kA_agg<<<ablocks, 256, 0, stream>>>(
                ybuf[i & 1], edges, bbase, agg, carry_val, carry_dst, E, B, W2n);
            kB_node<<<(N + 255) / 256, 256, 0, stream>>>(
                ybuf[i & 1], ybuf[(i + 1) & 1], agg, row_start, carry_dst, carry_val,
                b1[i], W2[i], b2[i], l[i], i < 4 ? W1[i + 1] : nullptr,
                ng, gacc, N, E, i == 4 ? 1 : 0);
        }
        k4_final<<<(G + 255) / 256, 256, 0, stream>>>(gacc, ng, out, N, G);
        return;
    }

    // fallback: R4 path (f32 rows, fused node-parallel layer)
    if (ws_size >= need_r4 && B <= 512) {
        float* y0 = (float*)d_ws;
        unsigned* pairs = (unsigned*)(y0 + regAB);
        float* y1 = (float*)pairs;
        unsigned* edges = pairs + reg2f;
        unsigned* row_start = edges + E;
        unsigned* bucket_cnt = row_start + (N + 1);
        unsigned* bbase = bucket_cnt + 512;
        unsigned* bcur = bbase + 513;
        float* gacc = (float*)(bcur + 512);

        hipMemsetAsync(bucket_cnt, 0, 512 * 4, stream);
        hipMemsetAsync(gacc, 0, (size_t)G * 4, stream);

        k1_hw1_f32<<<(N + 255) / 256, 256, 0, stream>>>(h, W1[0], y0, N);
        k_bhist<<<2048, 256, 0, stream>>>(dst, bucket_cnt, E);
        k_bscan<<<1, 512, 0, stream>>>(bucket_cnt, bbase, bcur, B);
        k_bscatter2<<<256, 1024, 0, stream>>>(src, dst, bcur, pairs, E, 256);
        k_p2<<<B, 1024, 0, stream>>>(pairs, bbase, edges, row_start, N, B, E, 0);

        float* ybuf[2] = {y0, y1};
        for (int i = 0; i < 5; i++) {
            k_layer<<<(N + 255) / 256, 256, 0, stream>>>(
                ybuf[i & 1], ybuf[(i + 1) & 1], row_start, edges,
                b1[i], W2[i], b2[i], l[i], i < 4 ? W1[i + 1] : nullptr,
                ng, gacc, N, i == 4 ? 1 : 0);
        }
        k4_final<<<(G + 255) / 256, 256, 0, stream>>>(gacc, ng, out, N, G);
    }
}